// Round 11
// baseline (2097.698 us; speedup 1.0000x reference)
//
#include <hip/hip_runtime.h>
#include <hip/hip_fp16.h>
#include <hip/hip_cooperative_groups.h>
#include <stdint.h>

namespace cg = cooperative_groups;

#define B_ 16
#define N_ 4096
#define S_ 1024
#define K_ 32
#define NQ_ (B_*S_)          // 16384
#define NPIX_ (NQ_*K_)       // 524288
#define OUTNP_ (NQ_*3)       // 49152 floats of new_xyz, then new_points
#define EPS_ 1e-5f

#define DPPMAX64(x, CTRL) do { \
  unsigned _lo = (unsigned)(x); unsigned _hi = (unsigned)((x)>>32); \
  unsigned _plo = (unsigned)__builtin_amdgcn_update_dpp((int)_lo,(int)_lo,(CTRL),0xF,0xF,false); \
  unsigned _phi = (unsigned)__builtin_amdgcn_update_dpp((int)_hi,(int)_hi,(CTRL),0xF,0xF,false); \
  unsigned long long _p = (((unsigned long long)_phi)<<32)|_plo; \
  if (_p > (x)) (x) = _p; \
} while(0)

#define DPPMAXF(r, CTRL) do { \
  float _t = __int_as_float(__builtin_amdgcn_update_dpp(__float_as_int(r),__float_as_int(r),(CTRL),0xF,0xF,false)); \
  (r) = fmaxf((r), _t); \
} while(0)

// ---------------- FPS (r8 frozen): 512 thr x 8 slots, DPP reduce, deferred output ----------------
__global__ __launch_bounds__(512) void k_fps(const float* __restrict__ xyz,
                                             float* __restrict__ out,
                                             float* __restrict__ nx) {
  const int b = blockIdx.x;
  const int t = threadIdx.x;
  const int lane = t & 63, wid = t >> 6;
  __shared__ int SX[N_], SY[N_], SZ[N_];
  __shared__ unsigned long long kbuf[2][8];
  const float* xb = xyz + (size_t)b * N_ * 3;
  for (int j = t; j < N_; j += 512) {
    SX[j] = (int)(xb[j*3+0] * 536870912.0f);   // x*2^29, exact
    SY[j] = (int)(xb[j*3+1] * 536870912.0f);
    SZ[j] = (int)(xb[j*3+2] * 536870912.0f);
  }
  __syncthreads();
  int PX[8], PY[8], PZ[8];
  unsigned long long key[8];
#pragma unroll
  for (int i = 0; i < 8; ++i) {
    const int j = t*8 + i;
    PX[i] = SX[j]; PY[i] = SY[j]; PZ[i] = SZ[j];
    key[i] = ~0ull;
  }
  int far = 0, farA = 0, farB = 0;
  for (int it = 0; it < S_; ++it) {
    if (it == t)       farA = far;
    if (it == t + 512) farB = far;
    if (it == S_-1) break;
    const int cx = SX[far], cy = SY[far], cz = SZ[far];
    unsigned long long best = 0;
#pragma unroll
    for (int i = 0; i < 8; ++i) {
      const int dx = PX[i]-cx, dy = PY[i]-cy, dz = PZ[i]-cz;
      unsigned long long nk = (unsigned long long)(unsigned)(4095 - (t*8 + i));
      nk += (unsigned long long)((long long)dx*dx);
      nk += (unsigned long long)((long long)dy*dy);
      nk += (unsigned long long)((long long)dz*dz);
      if (nk < key[i]) key[i] = nk;
      if (key[i] > best) best = key[i];
    }
    DPPMAX64(best, 0x111);
    DPPMAX64(best, 0x112);
    DPPMAX64(best, 0x114);
    DPPMAX64(best, 0x118);
    DPPMAX64(best, 0x142);
    DPPMAX64(best, 0x143);
    if (lane == 63) kbuf[it & 1][wid] = best;
    __syncthreads();
    unsigned long long g = kbuf[it & 1][lane & 7];
    DPPMAX64(g, 0x111); DPPMAX64(g, 0x112); DPPMAX64(g, 0x114);
    far = 4095 - (__builtin_amdgcn_readlane((int)(unsigned)g, 7) & 4095);
  }
  {
    const float s = 1.862645149230957e-9f;
    const float ax = (float)SX[farA]*s, ay = (float)SY[farA]*s, az = (float)SZ[farA]*s;
    const float bx = (float)SX[farB]*s, by = (float)SY[farB]*s, bz = (float)SZ[farB]*s;
    const int oA = (b*S_ + t)*3;
    const int oB = (b*S_ + t + 512)*3;
    out[oA] = ax; out[oA+1] = ay; out[oA+2] = az;
    nx[oA]  = ax; nx[oA+1]  = ay; nx[oA+2]  = az;
    out[oB] = bx; out[oB+1] = by; out[oB+2] = bz;
    nx[oB]  = bx; nx[oB+1]  = by; nx[oB+2]  = bz;
  }
}

// ---------------- ball query body (one query per wave call) ----------------
__device__ inline void ball_one(const int q, const int lane,
                                const float* __restrict__ xyz,
                                const float* __restrict__ nx,
                                int* __restrict__ idx) {
  const int b = q >> 10;
  const float* xb = xyz + (size_t)b * N_ * 3;
  const double qx = (double)nx[q*3+0], qy = (double)nx[q*3+1], qz = (double)nx[q*3+2];
  const double qq = qx*qx + qy*qy + qz*qz;
  const double r2 = 0.2 * 0.2;
  int found = 0, first_j = 0;
  bool have_first = false;
  for (int c = 0; c < N_/64; ++c) {
    const int j = c*64 + lane;
    const double px = (double)xb[j*3+0], py = (double)xb[j*3+1], pz = (double)xb[j*3+2];
    const double dot = px*qx + py*qy + pz*qz;
    const double pp  = px*px + py*py + pz*pz;
    const double d   = qq + pp - 2.0*dot;
    const bool hit = (d <= r2);
    const unsigned long long mask = __ballot(hit);
    if (!have_first && mask) { first_j = c*64 + (__ffsll(mask) - 1); have_first = true; }
    const int pos = found + (int)__popcll(mask & ((1ull << lane) - 1ull));
    if (hit && pos < K_) idx[q*K_ + pos] = j;
    found += (int)__popcll(mask);
    if (found >= K_) break;
  }
  const int cnt = found < K_ ? found : K_;
  if (lane >= cnt && lane < K_) idx[q*K_ + lane] = first_j;
}

// ================= MEGA: ball+prep -> momw -> fin0 -> s1 -> fin1 -> s2 -> fin2 -> s3 =================
__global__ __launch_bounds__(256) void k_mega(
    const float* __restrict__ xyz, const float* __restrict__ points,
    const float* __restrict__ w0, const float* __restrict__ b0,
    const float* __restrict__ g0, const float* __restrict__ be0,
    const float* __restrict__ w1, const float* __restrict__ b1,
    const float* __restrict__ g1, const float* __restrict__ be1,
    const float* __restrict__ w2, const float* __restrict__ b2,
    const float* __restrict__ g2, const float* __restrict__ be2,
    float* __restrict__ nx, int* __restrict__ idx,
    float* __restrict__ w0t, float* __restrict__ w1t, float* __restrict__ w2t,
    float* __restrict__ pr, float* __restrict__ momp,
    float* __restrict__ s1p, float* __restrict__ s2p,
    __half* __restrict__ a1, float* __restrict__ pooled)
{
  cg::grid_group gridg = cg::this_grid();
  __shared__ float smem[64][64];          // 16KB, re-carved per phase
  float* sm = &smem[0][0];
  const int tid = threadIdx.x;
  const int lane = tid & 63;
  const int wid = __builtin_amdgcn_readfirstlane(tid >> 6);
  const int nb = gridDim.x, bid = blockIdx.x;
  const int nwave = nb * 4, wgid = bid*4 + wid;

  // ---- P0: weight transpose (block 0) + ball query (all waves, wave-stride) ----
  if (bid == 0) {
    for (int i = tid; i < 64*6; i += 256)  { int o = i/6,  c = i%6;  w0t[c*64  + o] = w0[i]; }
    for (int i = tid; i < 64*64; i += 256) { int o = i>>6, c = i&63; w1t[c*64  + o] = w1[i]; }
    for (int i = tid; i < 128*64; i += 256){ int o = i>>6, c = i&63; w2t[c*128 + o] = w2[i]; }
  }
  for (int q = wgid; q < NQ_; q += nwave) ball_one(q, lane, xyz, nx, idx);
  gridg.sync();

  // ---- P1: moments of gathered 6-dim input, block-reduced -> momp[bid*32..] ----
  {
    float m[6] = {0,0,0,0,0,0};
    float M2[21];
#pragma unroll
    for (int u = 0; u < 21; ++u) M2[u] = 0.0f;
    for (int pix = bid*256 + tid; pix < NPIX_; pix += nb*256) {
      const int q = pix >> 5;
      const int b = q >> 10;
      const int j = idx[pix];
      const float* xp = xyz    + (size_t)(b*N_ + j)*3;
      const float* pq = points + (size_t)(b*N_ + j)*3;
      const float* nq = nx + q*3;
      float g[6];
      g[0] = xp[0]-nq[0]; g[1] = xp[1]-nq[1]; g[2] = xp[2]-nq[2];
      g[3] = pq[0]; g[4] = pq[1]; g[5] = pq[2];
#pragma unroll
      for (int i = 0; i < 6; ++i) m[i] += g[i];
      int u = 0;
#pragma unroll
      for (int i = 0; i < 6; ++i)
#pragma unroll
        for (int jj = i; jj < 6; ++jj) { M2[u] = fmaf(g[i], g[jj], M2[u]); ++u; }
    }
#pragma unroll
    for (int i = 0; i < 6; ++i)
#pragma unroll
      for (int s = 1; s < 64; s <<= 1) m[i] += __shfl_xor(m[i], s);
#pragma unroll
    for (int u = 0; u < 21; ++u)
#pragma unroll
      for (int s = 1; s < 64; s <<= 1) M2[u] += __shfl_xor(M2[u], s);
    if (lane == 0) {
      float* dst = sm + wid*32;
#pragma unroll
      for (int i = 0; i < 6; ++i) dst[i] = m[i];
#pragma unroll
      for (int u = 0; u < 21; ++u) dst[6+u] = M2[u];
#pragma unroll
      for (int u = 27; u < 32; ++u) dst[u] = 0.0f;
    }
    __syncthreads();
    if (tid < 32) momp[bid*32 + tid] = sm[tid] + sm[32+tid] + sm[64+tid] + sm[96+tid];
  }
  gridg.sync();

  // ---- P2: fin0 (block 0): reduce momp[nb][32] + closed-form BN0 params ----
  if (bid == 0) {
    // carve: part = sm[0..255] as [8][32], red = sm[256..287]
    const int c = tid & 31, p = tid >> 5;
    float a = 0.f;
    for (int w = p; w < nb; w += 8) a += momp[w*32 + c];
    sm[p*32 + c] = a;
    __syncthreads();
    if (tid < 32) {
      float s = 0.f;
#pragma unroll
      for (int pp = 0; pp < 8; ++pp) s += sm[pp*32 + c];
      sm[256 + c] = s;
    }
    __syncthreads();
    if (tid < 64) {
      const float inv = 1.0f / (float)NPIX_;
      float m1[6];
#pragma unroll
      for (int i = 0; i < 6; ++i) m1[i] = sm[256+i] * inv;
      float M2[6][6];
      int u = 0;
#pragma unroll
      for (int i = 0; i < 6; ++i)
#pragma unroll
        for (int jj = i; jj < 6; ++jj) { float v = sm[256+6+u]*inv; M2[i][jj] = v; M2[jj][i] = v; ++u; }
      float w[6];
#pragma unroll
      for (int i = 0; i < 6; ++i) w[i] = w0[tid*6+i];
      float ml = 0.0f;
#pragma unroll
      for (int i = 0; i < 6; ++i) ml += w[i]*m1[i];
      float e2 = 0.0f;
#pragma unroll
      for (int i = 0; i < 6; ++i)
#pragma unroll
        for (int jj = 0; jj < 6; ++jj) e2 += w[i]*w[jj]*M2[i][jj];
      const float var = e2 - ml*ml;
      const float mean = ml + b0[tid];
      const float sc = g0[tid] * rsqrtf(var + EPS_);
      pr[tid] = sc; pr[64+tid] = be0[tid] - mean*sc;
    }
  }
  gridg.sync();

  // ---- P3: s1 (tile-stride): gather -> l0 -> bn0relu -> LDS -> l1 -> s1p + a1 fp16 ----
  {
    const int c0 = wid * 16;
    float b0r[16], b1r[16], p0s[16], p0h[16];
#pragma unroll
    for (int u = 0; u < 16; ++u) {
      b0r[u] = b0[c0+u]; b1r[u] = b1[c0+u];
      p0s[u] = pr[c0+u]; p0h[u] = pr[64+c0+u];
    }
    float s1a[16], s1b[16];
#pragma unroll
    for (int u = 0; u < 16; ++u) { s1a[u] = 0.0f; s1b[u] = 0.0f; }
    for (int tile = bid; tile < NQ_/2; tile += nb) {
      const int q = tile*2 + (lane >> 5);
      const int k = lane & 31;
      const int b = q >> 10;
      const int j = idx[q*K_ + k];
      const float* xp = xyz    + (size_t)(b*N_ + j)*3;
      const float* pp = points + (size_t)(b*N_ + j)*3;
      const float* nq = nx + q*3;
      float g[6];
      g[0] = xp[0]-nq[0]; g[1] = xp[1]-nq[1]; g[2] = xp[2]-nq[2];
      g[3] = pp[0];       g[4] = pp[1];       g[5] = pp[2];
      float acc[16];
#pragma unroll
      for (int u = 0; u < 16; ++u) acc[u] = b0r[u];
#pragma unroll
      for (int i = 0; i < 6; ++i) {
        const float* w = w0t + i*64 + c0;
#pragma unroll
        for (int u = 0; u < 16; ++u) acc[u] = fmaf(w[u], g[i], acc[u]);
      }
#pragma unroll
      for (int u = 0; u < 16; ++u)
        smem[c0+u][lane] = fmaxf(fmaf(p0s[u], acc[u], p0h[u]), 0.0f);
      __syncthreads();
#pragma unroll
      for (int u = 0; u < 16; ++u) acc[u] = b1r[u];
#pragma unroll 8
      for (int ci = 0; ci < 64; ++ci) {
        const float av = smem[ci][lane];
        const float* w = w1t + ci*64 + c0;
#pragma unroll
        for (int u = 0; u < 16; ++u) acc[u] = fmaf(w[u], av, acc[u]);
      }
      const int pix = tile*64 + lane;
#pragma unroll
      for (int u = 0; u < 16; ++u) {
        s1a[u] += acc[u]; s1b[u] = fmaf(acc[u], acc[u], s1b[u]);
        a1[(size_t)(c0+u)*NPIX_ + pix] = __float2half(acc[u]);
      }
      __syncthreads();
    }
#pragma unroll
    for (int u = 0; u < 16; ++u) {
      float a = s1a[u], bq = s1b[u];
#pragma unroll
      for (int s = 1; s < 64; s <<= 1) { a += __shfl_xor(a, s); bq += __shfl_xor(bq, s); }
      s1a[u] = a; s1b[u] = bq;
    }
    if (lane == 0) {
      float* dst = s1p + (bid*4 + wid)*32;
#pragma unroll
      for (int u = 0; u < 16; ++u) { dst[u] = s1a[u]; dst[16+u] = s1b[u]; }
    }
  }
  gridg.sync();

  // ---- P4: fin1 (block 0): reduce s1p[nb*4][32] -> BN1 params ----
  if (bid == 0) {
    // carve: pa = sm[0..255] [4][64], pb = sm[256..511] [4][64]
    const int c = tid & 63, p = tid >> 6;
    const int wq = c >> 4, u = c & 15;
    float sa = 0.f, sb = 0.f;
    for (int blk = p; blk < nb; blk += 4) {
      const int w = blk*4 + wq;
      sa += s1p[w*32 + u];
      sb += s1p[w*32 + 16 + u];
    }
    sm[p*64 + c] = sa; sm[256 + p*64 + c] = sb;
    __syncthreads();
    if (tid < 64) {
      const float A  = sm[tid] + sm[64+tid] + sm[128+tid] + sm[192+tid];
      const float Bq = sm[256+tid] + sm[256+64+tid] + sm[256+128+tid] + sm[256+192+tid];
      const float inv = 1.0f / (float)NPIX_;
      const float mean = A*inv;
      const float var = Bq*inv - mean*mean;
      const float sc = g1[tid] * rsqrtf(var + EPS_);
      pr[128+tid] = sc; pr[192+tid] = be1[tid] - mean*sc;
    }
  }
  gridg.sync();

  // ---- P5: s2 (tile-stride): a1 fp16 -> bn1relu -> LDS -> l2 -> s2p + pooled ----
  {
    const int cl = wid * 16;
    const int c20 = wid * 32;
    float p1s[16], p1h[16], b2r[32];
    bool g2p[32];
#pragma unroll
    for (int u = 0; u < 16; ++u) { p1s[u] = pr[128+cl+u]; p1h[u] = pr[192+cl+u]; }
#pragma unroll
    for (int u = 0; u < 32; ++u) { b2r[u] = b2[c20+u]; g2p[u] = (g2[c20+u] >= 0.0f); }
    float s2a[32], s2b[32];
#pragma unroll
    for (int u = 0; u < 32; ++u) { s2a[u] = 0.0f; s2b[u] = 0.0f; }
    for (int tile = bid; tile < NQ_/2; tile += nb) {
      const int pixb = tile*64;
#pragma unroll
      for (int u = 0; u < 16; ++u) {
        const float v = __half2float(a1[(size_t)(cl+u)*NPIX_ + pixb + lane]);
        smem[cl+u][lane] = fmaxf(fmaf(p1s[u], v, p1h[u]), 0.0f);
      }
      __syncthreads();
      float acc2[32];
#pragma unroll
      for (int u = 0; u < 32; ++u) acc2[u] = b2r[u];
#pragma unroll 8
      for (int ci = 0; ci < 64; ++ci) {
        const float av = smem[ci][lane];
        const float* w = w2t + ci*128 + c20;
#pragma unroll
        for (int u = 0; u < 32; ++u) acc2[u] = fmaf(w[u], av, acc2[u]);
      }
      const int q = tile*2 + (lane >> 5);
#pragma unroll
      for (int u = 0; u < 32; ++u) {
        s2a[u] += acc2[u]; s2b[u] = fmaf(acc2[u], acc2[u], s2b[u]);
        float r = g2p[u] ? acc2[u] : -acc2[u];
        DPPMAXF(r, 0xB1);
        DPPMAXF(r, 0x4E);
        DPPMAXF(r, 0x141);
        DPPMAXF(r, 0x140);
        DPPMAXF(r, 0x142);
        if ((lane & 31) == 31) pooled[q*128 + c20 + u] = g2p[u] ? r : -r;
      }
      __syncthreads();
    }
#pragma unroll
    for (int u = 0; u < 32; ++u) {
      float a = s2a[u], bq = s2b[u];
#pragma unroll
      for (int s = 1; s < 64; s <<= 1) { a += __shfl_xor(a, s); bq += __shfl_xor(bq, s); }
      s2a[u] = a; s2b[u] = bq;
    }
    if (lane == 0) {
      float* dst = s2p + (bid*4 + wid)*64;
#pragma unroll
      for (int u = 0; u < 32; ++u) { dst[u] = s2a[u]; dst[32+u] = s2b[u]; }
    }
  }
  gridg.sync();

  // ---- P6: fin2 (block 0): reduce s2p[nb*4][64] -> BN2 params ----
  if (bid == 0) {
    const int c = tid & 127, p = tid >> 7;
    const int wq = c >> 5, u = c & 31;
    float sa = 0.f, sb = 0.f;
    for (int blk = p; blk < nb; blk += 2) {
      const int w = blk*4 + wq;
      sa += s2p[w*64 + u];
      sb += s2p[w*64 + 32 + u];
    }
    sm[p*128 + c] = sa; sm[256 + p*128 + c] = sb;
    __syncthreads();
    if (tid < 128) {
      const float A  = sm[tid] + sm[128+tid];
      const float Bq = sm[256+tid] + sm[256+128+tid];
      const float inv = 1.0f / (float)NPIX_;
      const float mean = A*inv;
      const float var = Bq*inv - mean*mean;
      const float sc = g2[tid] * rsqrtf(var + EPS_);
      pr[256+tid] = sc; pr[384+tid] = be2[tid] - mean*sc;
    }
  }
  gridg.sync();

  // ---- P7: s3 in-place: bn2 affine -> relu over pooled (= out+OUTNP_) ----
  for (int g = bid*256 + tid; g < NQ_*128; g += nb*256) {
    const int c = g & 127;
    pooled[g] = fmaxf(fmaf(pr[256+c], pooled[g], pr[384+c]), 0.0f);
  }
}

// ================= FALLBACK kernels (r10 proven path) =================
__global__ __launch_bounds__(256) void k_ball(const float* __restrict__ xyz,
                                              const float* __restrict__ nx,
                                              int* __restrict__ idx,
                                              const float* __restrict__ w0,
                                              const float* __restrict__ w1,
                                              const float* __restrict__ w2,
                                              float* __restrict__ w0t,
                                              float* __restrict__ w1t,
                                              float* __restrict__ w2t) {
  if (blockIdx.x == NQ_/4) {
    const int t = threadIdx.x;
    for (int i = t; i < 64*6; i += 256)  { int o = i/6,  c = i%6;  w0t[c*64  + o] = w0[i]; }
    for (int i = t; i < 64*64; i += 256) { int o = i>>6, c = i&63; w1t[c*64  + o] = w1[i]; }
    for (int i = t; i < 128*64; i += 256){ int o = i>>6, c = i&63; w2t[c*128 + o] = w2[i]; }
    return;
  }
  const int lane = threadIdx.x & 63;
  const int q = blockIdx.x * 4 + (threadIdx.x >> 6);
  ball_one(q, lane, xyz, nx, idx);
}

__global__ __launch_bounds__(256) void k_momw(const float* __restrict__ xyz,
                                              const float* __restrict__ points,
                                              const float* __restrict__ nx,
                                              const int* __restrict__ idx,
                                              float* __restrict__ momp) {
  const int tid = blockIdx.x * blockDim.x + threadIdx.x;
  float m[6] = {0,0,0,0,0,0};
  float M2[21];
#pragma unroll
  for (int u = 0; u < 21; ++u) M2[u] = 0.0f;
  int js[8], qs[8];
#pragma unroll
  for (int r = 0; r < 8; ++r) {
    const int pix = tid + (r << 16);
    js[r] = idx[pix]; qs[r] = pix >> 5;
  }
#pragma unroll
  for (int r = 0; r < 8; ++r) {
    const int b = qs[r] >> 10;
    const float* xp = xyz    + (size_t)(b*N_ + js[r])*3;
    const float* pq = points + (size_t)(b*N_ + js[r])*3;
    const float* nq = nx + qs[r]*3;
    float g[6];
    g[0] = xp[0]-nq[0]; g[1] = xp[1]-nq[1]; g[2] = xp[2]-nq[2];
    g[3] = pq[0]; g[4] = pq[1]; g[5] = pq[2];
#pragma unroll
    for (int i = 0; i < 6; ++i) m[i] += g[i];
    int u = 0;
#pragma unroll
    for (int i = 0; i < 6; ++i)
#pragma unroll
      for (int jj = i; jj < 6; ++jj) { M2[u] = fmaf(g[i], g[jj], M2[u]); ++u; }
  }
#pragma unroll
  for (int i = 0; i < 6; ++i)
#pragma unroll
    for (int s = 1; s < 64; s <<= 1) m[i] += __shfl_xor(m[i], s);
#pragma unroll
  for (int u = 0; u < 21; ++u)
#pragma unroll
    for (int s = 1; s < 64; s <<= 1) M2[u] += __shfl_xor(M2[u], s);
  if ((threadIdx.x & 63) == 0) {
    const int w = blockIdx.x * 4 + (threadIdx.x >> 6);
    float* dst = momp + w*32;
#pragma unroll
    for (int i = 0; i < 6; ++i) dst[i] = m[i];
#pragma unroll
    for (int u = 0; u < 21; ++u) dst[6+u] = M2[u];
  }
}

__global__ void k_fin0r(const float* __restrict__ momp,
                        const float* __restrict__ w0, const float* __restrict__ b0,
                        const float* __restrict__ g0, const float* __restrict__ be0,
                        float* __restrict__ pr, int nent) {
  __shared__ float part[8][32];
  __shared__ float red[32];
  const int t = threadIdx.x;
  const int c = t & 31, p = t >> 5;
  float a = 0.f;
  for (int w = p; w < nent; w += 8) a += momp[w*32 + c];
  part[p][c] = a;
  __syncthreads();
  if (t < 32) {
    float s = 0.f;
#pragma unroll
    for (int pp = 0; pp < 8; ++pp) s += part[pp][c];
    red[c] = s;
  }
  __syncthreads();
  if (t < 64) {
    const float inv = 1.0f / (float)NPIX_;
    float m1[6];
#pragma unroll
    for (int i = 0; i < 6; ++i) m1[i] = red[i] * inv;
    float M2[6][6];
    int u = 0;
#pragma unroll
    for (int i = 0; i < 6; ++i)
#pragma unroll
      for (int jj = i; jj < 6; ++jj) { float v = red[6+u]*inv; M2[i][jj] = v; M2[jj][i] = v; ++u; }
    float w[6];
#pragma unroll
    for (int i = 0; i < 6; ++i) w[i] = w0[t*6+i];
    float ml = 0.0f;
#pragma unroll
    for (int i = 0; i < 6; ++i) ml += w[i]*m1[i];
    float e2 = 0.0f;
#pragma unroll
    for (int i = 0; i < 6; ++i)
#pragma unroll
      for (int jj = 0; jj < 6; ++jj) e2 += w[i]*w[jj]*M2[i][jj];
    const float var = e2 - ml*ml;
    const float mean = ml + b0[t];
    const float sc = g0[t] * rsqrtf(var + EPS_);
    pr[t] = sc; pr[64+t] = be0[t] - mean*sc;
  }
}

__global__ void k_fin1r(const float* __restrict__ s1p,
                        const float* __restrict__ g1, const float* __restrict__ be1,
                        float* __restrict__ pr, int nblk) {
  __shared__ float pa[4][64], pb[4][64];
  const int t = threadIdx.x;
  const int c = t & 63, p = t >> 6;
  const int wq = c >> 4, u = c & 15;
  float sa = 0.f, sb = 0.f;
  for (int blk = p; blk < nblk; blk += 4) {
    const int w = blk*4 + wq;
    sa += s1p[w*32 + u];
    sb += s1p[w*32 + 16 + u];
  }
  pa[p][c] = sa; pb[p][c] = sb;
  __syncthreads();
  if (t < 64) {
    const float A  = pa[0][t]+pa[1][t]+pa[2][t]+pa[3][t];
    const float Bq = pb[0][t]+pb[1][t]+pb[2][t]+pb[3][t];
    const float inv = 1.0f / (float)NPIX_;
    const float mean = A*inv;
    const float var = Bq*inv - mean*mean;
    const float sc = g1[t] * rsqrtf(var + EPS_);
    pr[128+t] = sc; pr[192+t] = be1[t] - mean*sc;
  }
}

__global__ void k_fin2r(const float* __restrict__ s2p,
                        const float* __restrict__ g2, const float* __restrict__ be2,
                        float* __restrict__ pr, int nblk) {
  __shared__ float pa[2][128], pb[2][128];
  const int t = threadIdx.x;
  const int c = t & 127, p = t >> 7;
  const int wq = c >> 5, u = c & 31;
  float sa = 0.f, sb = 0.f;
  for (int blk = p; blk < nblk; blk += 2) {
    const int w = blk*4 + wq;
    sa += s2p[w*64 + u];
    sb += s2p[w*64 + 32 + u];
  }
  pa[p][c] = sa; pb[p][c] = sb;
  __syncthreads();
  if (t < 128) {
    const float A  = pa[0][t]+pa[1][t];
    const float Bq = pb[0][t]+pb[1][t];
    const float inv = 1.0f / (float)NPIX_;
    const float mean = A*inv;
    const float var = Bq*inv - mean*mean;
    const float sc = g2[t] * rsqrtf(var + EPS_);
    pr[256+t] = sc; pr[384+t] = be2[t] - mean*sc;
  }
}

__global__ __launch_bounds__(256) void k_s1(
    const float* __restrict__ xyz, const float* __restrict__ points,
    const float* __restrict__ nx, const int* __restrict__ idx,
    const float* __restrict__ w0t, const float* __restrict__ w1t,
    const float* __restrict__ b0, const float* __restrict__ b1,
    const float* __restrict__ pr, float* __restrict__ s1p,
    __half* __restrict__ a1)
{
  __shared__ float a0T[64][64];
  const int tid = threadIdx.x;
  const int lane = tid & 63;
  const int wid = __builtin_amdgcn_readfirstlane(tid >> 6);
  const int c0 = wid * 16;
  float b0r[16], b1r[16], p0s[16], p0h[16];
#pragma unroll
  for (int u = 0; u < 16; ++u) {
    b0r[u] = b0[c0+u]; b1r[u] = b1[c0+u];
    p0s[u] = pr[c0+u]; p0h[u] = pr[64+c0+u];
  }
  float s1a[16], s1b[16];
#pragma unroll
  for (int u = 0; u < 16; ++u) { s1a[u] = 0.0f; s1b[u] = 0.0f; }
  for (int tile = blockIdx.x; tile < NQ_/2; tile += gridDim.x) {
    const int q = tile*2 + (lane >> 5);
    const int k = lane & 31;
    const int b = q >> 10;
    const int j = idx[q*K_ + k];
    const float* xp = xyz    + (size_t)(b*N_ + j)*3;
    const float* pp = points + (size_t)(b*N_ + j)*3;
    const float* nq = nx + q*3;
    float g[6];
    g[0] = xp[0]-nq[0]; g[1] = xp[1]-nq[1]; g[2] = xp[2]-nq[2];
    g[3] = pp[0];       g[4] = pp[1];       g[5] = pp[2];
    float acc[16];
#pragma unroll
    for (int u = 0; u < 16; ++u) acc[u] = b0r[u];
#pragma unroll
    for (int i = 0; i < 6; ++i) {
      const float* w = w0t + i*64 + c0;
#pragma unroll
      for (int u = 0; u < 16; ++u) acc[u] = fmaf(w[u], g[i], acc[u]);
    }
#pragma unroll
    for (int u = 0; u < 16; ++u)
      a0T[c0+u][lane] = fmaxf(fmaf(p0s[u], acc[u], p0h[u]), 0.0f);
    __syncthreads();
#pragma unroll
    for (int u = 0; u < 16; ++u) acc[u] = b1r[u];
#pragma unroll 8
    for (int ci = 0; ci < 64; ++ci) {
      const float av = a0T[ci][lane];
      const float* w = w1t + ci*64 + c0;
#pragma unroll
      for (int u = 0; u < 16; ++u) acc[u] = fmaf(w[u], av, acc[u]);
    }
    const int pix = tile*64 + lane;
#pragma unroll
    for (int u = 0; u < 16; ++u) {
      s1a[u] += acc[u]; s1b[u] = fmaf(acc[u], acc[u], s1b[u]);
      a1[(size_t)(c0+u)*NPIX_ + pix] = __float2half(acc[u]);
    }
    __syncthreads();
  }
#pragma unroll
  for (int u = 0; u < 16; ++u) {
    float a = s1a[u], bq = s1b[u];
#pragma unroll
    for (int s = 1; s < 64; s <<= 1) { a += __shfl_xor(a, s); bq += __shfl_xor(bq, s); }
    s1a[u] = a; s1b[u] = bq;
  }
  if (lane == 0) {
    float* dst = s1p + (blockIdx.x*4 + wid)*32;
#pragma unroll
    for (int u = 0; u < 16; ++u) { dst[u] = s1a[u]; dst[16+u] = s1b[u]; }
  }
}

__global__ __launch_bounds__(256) void k_s2(
    const __half* __restrict__ a1, const float* __restrict__ w2t,
    const float* __restrict__ b2, const float* __restrict__ g2,
    const float* __restrict__ pr, float* __restrict__ s2p,
    float* __restrict__ pooled)
{
  __shared__ float a1T[64][64];
  const int tid = threadIdx.x;
  const int lane = tid & 63;
  const int wid = __builtin_amdgcn_readfirstlane(tid >> 6);
  const int cl = wid * 16;
  const int c20 = wid * 32;
  float p1s[16], p1h[16], b2r[32];
  bool g2p[32];
#pragma unroll
  for (int u = 0; u < 16; ++u) { p1s[u] = pr[128+cl+u]; p1h[u] = pr[192+cl+u]; }
#pragma unroll
  for (int u = 0; u < 32; ++u) { b2r[u] = b2[c20+u]; g2p[u] = (g2[c20+u] >= 0.0f); }
  float s2a[32], s2b[32];
#pragma unroll
  for (int u = 0; u < 32; ++u) { s2a[u] = 0.0f; s2b[u] = 0.0f; }
  for (int tile = blockIdx.x; tile < NQ_/2; tile += gridDim.x) {
    const int pixb = tile*64;
#pragma unroll
    for (int u = 0; u < 16; ++u) {
      const float v = __half2float(a1[(size_t)(cl+u)*NPIX_ + pixb + lane]);
      a1T[cl+u][lane] = fmaxf(fmaf(p1s[u], v, p1h[u]), 0.0f);
    }
    __syncthreads();
    float acc2[32];
#pragma unroll
    for (int u = 0; u < 32; ++u) acc2[u] = b2r[u];
#pragma unroll 8
    for (int ci = 0; ci < 64; ++ci) {
      const float av = a1T[ci][lane];
      const float* w = w2t + ci*128 + c20;
#pragma unroll
      for (int u = 0; u < 32; ++u) acc2[u] = fmaf(w[u], av, acc2[u]);
    }
    const int q = tile*2 + (lane >> 5);
#pragma unroll
    for (int u = 0; u < 32; ++u) {
      s2a[u] += acc2[u]; s2b[u] = fmaf(acc2[u], acc2[u], s2b[u]);
      float r = g2p[u] ? acc2[u] : -acc2[u];
      DPPMAXF(r, 0xB1);
      DPPMAXF(r, 0x4E);
      DPPMAXF(r, 0x141);
      DPPMAXF(r, 0x140);
      DPPMAXF(r, 0x142);
      if ((lane & 31) == 31) pooled[q*128 + c20 + u] = g2p[u] ? r : -r;
    }
    __syncthreads();
  }
#pragma unroll
  for (int u = 0; u < 32; ++u) {
    float a = s2a[u], bq = s2b[u];
#pragma unroll
    for (int s = 1; s < 64; s <<= 1) { a += __shfl_xor(a, s); bq += __shfl_xor(bq, s); }
    s2a[u] = a; s2b[u] = bq;
  }
  if (lane == 0) {
    float* dst = s2p + (blockIdx.x*4 + wid)*64;
#pragma unroll
    for (int u = 0; u < 32; ++u) { dst[u] = s2a[u]; dst[32+u] = s2b[u]; }
  }
}

__global__ __launch_bounds__(256) void k_s3(const float* __restrict__ pr,
                                            float* __restrict__ outnp) {
  const int g = blockIdx.x * 256 + threadIdx.x;
  const int c = g & 127;
  const float y = fmaf(pr[256+c], outnp[g], pr[384+c]);
  outnp[g] = fmaxf(y, 0.0f);
}

extern "C" void kernel_launch(void* const* d_in, const int* in_sizes, int n_in,
                              void* d_out, int out_size, void* d_ws, size_t ws_size,
                              hipStream_t stream) {
  const float* xyz    = (const float*)d_in[0];
  const float* points = (const float*)d_in[1];
  const float* w0  = (const float*)d_in[2];
  const float* b0  = (const float*)d_in[3];
  const float* g0  = (const float*)d_in[4];
  const float* be0 = (const float*)d_in[5];
  const float* w1  = (const float*)d_in[6];
  const float* b1  = (const float*)d_in[7];
  const float* g1  = (const float*)d_in[8];
  const float* be1 = (const float*)d_in[9];
  const float* w2  = (const float*)d_in[10];
  const float* b2  = (const float*)d_in[11];
  const float* g2  = (const float*)d_in[12];
  const float* be2 = (const float*)d_in[13];
  float* out = (float*)d_out;
  float* ws  = (float*)d_ws;

  float* nx  = ws;                       // 49152
  int*   idx = (int*)(ws + 49152);       // 524288 ints
  float* w0t = ws + 573440;
  float* w1t = ws + 573824;
  float* w2t = ws + 577920;
  float* pr  = ws + 586624;              // 512 floats
  __half* a1 = (__half*)(ws + 2684928);  // 33554432 halfs (67MB)
  float* momp = ws + 587264;             // up to 1024*32
  float* s1p  = ws + 587264 + 32768;     // up to 4096*32
  float* s2p  = (float*)(ws + 49152);    // up to 4096*64 aliases idx (dead after s1)
  float* pooled = out + OUTNP_;          // s2 writes pre-BN pooled; s3 finishes in place

  const size_t need = (size_t)(2684928) * sizeof(float) + (size_t)33554432 * sizeof(__half);
  const bool big = ws_size >= need;

  k_fps<<<B_, 512, 0, stream>>>(xyz, out, nx);

  bool done = false;
  if (big) {
    int occ = 0;
    if (hipOccupancyMaxActiveBlocksPerMultiprocessor(&occ, k_mega, 256, 0) == hipSuccess && occ > 0) {
      int nb = occ * 256;             // 256 CUs
      if (nb > 1024) nb = 1024;
      void* args[] = {
        (void*)&xyz, (void*)&points,
        (void*)&w0, (void*)&b0, (void*)&g0, (void*)&be0,
        (void*)&w1, (void*)&b1, (void*)&g1, (void*)&be1,
        (void*)&w2, (void*)&b2, (void*)&g2, (void*)&be2,
        (void*)&nx, (void*)&idx,
        (void*)&w0t, (void*)&w1t, (void*)&w2t,
        (void*)&pr, (void*)&momp, (void*)&s1p, (void*)&s2p,
        (void*)&a1, (void*)&pooled
      };
      if (hipLaunchCooperativeKernel((const void*)k_mega, dim3(nb), dim3(256),
                                     args, 0, stream) == hipSuccess) {
        done = true;
      }
    }
  }
  if (!done && big) {
    const int NB = 1024;
    k_ball<<<NQ_/4 + 1, 256, 0, stream>>>(xyz, nx, idx, w0, w1, w2, w0t, w1t, w2t);
    k_momw<<<256, 256, 0, stream>>>(xyz, points, nx, idx, momp);
    k_fin0r<<<1, 256, 0, stream>>>(momp, w0, b0, g0, be0, pr, 1024);
    k_s1<<<NB, 256, 0, stream>>>(xyz, points, nx, idx, w0t, w1t, b0, b1, pr, s1p, a1);
    k_fin1r<<<1, 256, 0, stream>>>(s1p, g1, be1, pr, NB);
    k_s2<<<NB, 256, 0, stream>>>(a1, w2t, b2, g2, pr, s2p, pooled);
    k_fin2r<<<1, 256, 0, stream>>>(s2p, g2, be2, pr, NB);
    k_s3<<<NPIX_*4/256, 256, 0, stream>>>(pr, pooled);
  }
}

// Round 12
// 1243.052 us; speedup vs baseline: 1.6875x; 1.6875x over previous
//
#include <hip/hip_runtime.h>
#include <hip/hip_fp16.h>
#include <stdint.h>

#define B_ 16
#define N_ 4096
#define S_ 1024
#define K_ 32
#define NQ_ (B_*S_)          // 16384
#define NPIX_ (NQ_*K_)       // 524288
#define OUTNP_ (NQ_*3)       // 49152 floats of new_xyz, then new_points
#define EPS_ 1e-5f

// ws layout (floats):
// [0, 49152)            new_xyz copy
// [49152, 573440)       idx (int32) NPIX_          [s2p (4096*64 f32) aliases here after s1]
// [573440, 573824)      w0t  (6 x 64)
// [573824, 577920)      w1t  (64 x 64)
// [577920, 586112)      w2t  (64 x 128)
// [586112, 586624)      st (atomic stats, fallback path only)
// [586624, 587136)      pr: scale0[64] shift0[64] scale1[64] shift1[64] scale2[128] shift2[128]
// [587264, 2684416)     momp (1024*32) + s1p (4096*32)   [pooled lives in d_out]
// [2684928, ...)        a1_pre fp16 PIXEL-major [NPIX][64] (67MB)

#define DPPMAX64(x, CTRL) do { \
  unsigned _lo = (unsigned)(x); unsigned _hi = (unsigned)((x)>>32); \
  unsigned _plo = (unsigned)__builtin_amdgcn_update_dpp((int)_lo,(int)_lo,(CTRL),0xF,0xF,false); \
  unsigned _phi = (unsigned)__builtin_amdgcn_update_dpp((int)_hi,(int)_hi,(CTRL),0xF,0xF,false); \
  unsigned long long _p = (((unsigned long long)_phi)<<32)|_plo; \
  if (_p > (x)) (x) = _p; \
} while(0)

#define DPPMAXF(r, CTRL) do { \
  float _t = __int_as_float(__builtin_amdgcn_update_dpp(__float_as_int(r),__float_as_int(r),(CTRL),0xF,0xF,false)); \
  (r) = fmaxf((r), _t); \
} while(0)

// ---------------- FPS (r8 frozen): 512 thr x 8 slots, DPP reduce, deferred output ----------------
// coords pre-shifted: int(x*2^29) exact (x = k*2^-23, k<2^23). dx^2 sums carry a
// free <<12, so key = sum(sq) + (4095-idx) == (dist<<12)|tag exactly.
// u64 max == argmax with lowest-index tie-break, bit-identical to f64 numpy.
__global__ __launch_bounds__(512) void k_fps(const float* __restrict__ xyz,
                                             float* __restrict__ out,
                                             float* __restrict__ nx) {
  const int b = blockIdx.x;
  const int t = threadIdx.x;
  const int lane = t & 63, wid = t >> 6;
  __shared__ int SX[N_], SY[N_], SZ[N_];
  __shared__ unsigned long long kbuf[2][8];
  const float* xb = xyz + (size_t)b * N_ * 3;
  for (int j = t; j < N_; j += 512) {
    SX[j] = (int)(xb[j*3+0] * 536870912.0f);   // x*2^29, exact
    SY[j] = (int)(xb[j*3+1] * 536870912.0f);
    SZ[j] = (int)(xb[j*3+2] * 536870912.0f);
  }
  __syncthreads();
  int PX[8], PY[8], PZ[8];
  unsigned long long key[8];
#pragma unroll
  for (int i = 0; i < 8; ++i) {
    const int j = t*8 + i;
    PX[i] = SX[j]; PY[i] = SY[j]; PZ[i] = SZ[j];
    key[i] = ~0ull;
  }
  int far = 0, farA = 0, farB = 0;
  for (int it = 0; it < S_; ++it) {
    if (it == t)       farA = far;
    if (it == t + 512) farB = far;
    if (it == S_-1) break;
    const int cx = SX[far], cy = SY[far], cz = SZ[far];
    unsigned long long best = 0;
#pragma unroll
    for (int i = 0; i < 8; ++i) {
      const int dx = PX[i]-cx, dy = PY[i]-cy, dz = PZ[i]-cz;
      unsigned long long nk = (unsigned long long)(unsigned)(4095 - (t*8 + i));
      nk += (unsigned long long)((long long)dx*dx);
      nk += (unsigned long long)((long long)dy*dy);
      nk += (unsigned long long)((long long)dz*dz);
      if (nk < key[i]) key[i] = nk;
      if (key[i] > best) best = key[i];
    }
    DPPMAX64(best, 0x111);
    DPPMAX64(best, 0x112);
    DPPMAX64(best, 0x114);
    DPPMAX64(best, 0x118);
    DPPMAX64(best, 0x142);
    DPPMAX64(best, 0x143);
    if (lane == 63) kbuf[it & 1][wid] = best;
    __syncthreads();
    unsigned long long g = kbuf[it & 1][lane & 7];
    DPPMAX64(g, 0x111); DPPMAX64(g, 0x112); DPPMAX64(g, 0x114);
    far = 4095 - (__builtin_amdgcn_readlane((int)(unsigned)g, 7) & 4095);
  }
  {
    const float s = 1.862645149230957e-9f;
    const float ax = (float)SX[farA]*s, ay = (float)SY[farA]*s, az = (float)SZ[farA]*s;
    const float bx = (float)SX[farB]*s, by = (float)SY[farB]*s, bz = (float)SZ[farB]*s;
    const int oA = (b*S_ + t)*3;
    const int oB = (b*S_ + t + 512)*3;
    out[oA] = ax; out[oA+1] = ay; out[oA+2] = az;
    nx[oA]  = ax; nx[oA+1]  = ay; nx[oA+2]  = az;
    out[oB] = bx; out[oB+1] = by; out[oB+2] = bz;
    nx[oB]  = bx; nx[oB+1]  = by; nx[oB+2]  = bz;
  }
}

// ---------------- Ball query (+ merged weight-transpose prep block) ----------------
__global__ __launch_bounds__(256) void k_ball(const float* __restrict__ xyz,
                                              const float* __restrict__ nx,
                                              int* __restrict__ idx,
                                              const float* __restrict__ w0,
                                              const float* __restrict__ w1,
                                              const float* __restrict__ w2,
                                              float* __restrict__ w0t,
                                              float* __restrict__ w1t,
                                              float* __restrict__ w2t) {
  if (blockIdx.x == NQ_/4) {   // prep block: transpose weights
    const int t = threadIdx.x;
    for (int i = t; i < 64*6; i += 256)  { int o = i/6,  c = i%6;  w0t[c*64  + o] = w0[i]; }
    for (int i = t; i < 64*64; i += 256) { int o = i>>6, c = i&63; w1t[c*64  + o] = w1[i]; }
    for (int i = t; i < 128*64; i += 256){ int o = i>>6, c = i&63; w2t[c*128 + o] = w2[i]; }
    return;
  }
  const int lane = threadIdx.x & 63;
  const int q = blockIdx.x * 4 + (threadIdx.x >> 6);
  const int b = q >> 10;
  const float* xb = xyz + (size_t)b * N_ * 3;
  const double qx = (double)nx[q*3+0], qy = (double)nx[q*3+1], qz = (double)nx[q*3+2];
  const double qq = qx*qx + qy*qy + qz*qz;
  const double r2 = 0.2 * 0.2;
  int found = 0, first_j = 0;
  bool have_first = false;
  for (int c = 0; c < N_/64; ++c) {
    const int j = c*64 + lane;
    const double px = (double)xb[j*3+0], py = (double)xb[j*3+1], pz = (double)xb[j*3+2];
    const double dot = px*qx + py*qy + pz*qz;            // exact
    const double pp  = px*px + py*py + pz*pz;            // exact
    const double d   = qq + pp - 2.0*dot;                // exact
    const bool hit = (d <= r2);
    const unsigned long long mask = __ballot(hit);
    if (!have_first && mask) { first_j = c*64 + (__ffsll(mask) - 1); have_first = true; }
    const int pos = found + (int)__popcll(mask & ((1ull << lane) - 1ull));
    if (hit && pos < K_) idx[q*K_ + pos] = j;
    found += (int)__popcll(mask);
    if (found >= K_) break;
  }
  const int cnt = found < K_ ? found : K_;
  if (lane >= cnt && lane < K_) idx[q*K_ + lane] = first_j;
}

// ---------------- Moments of gathered 6-dim input: per-wave partial STORES ----------------
__global__ __launch_bounds__(256) void k_momw(const float* __restrict__ xyz,
                                              const float* __restrict__ points,
                                              const float* __restrict__ nx,
                                              const int* __restrict__ idx,
                                              float* __restrict__ momp) {
  const int tid = blockIdx.x * blockDim.x + threadIdx.x;   // 65536 threads, 8 px each
  float m[6] = {0,0,0,0,0,0};
  float M2[21];
#pragma unroll
  for (int u = 0; u < 21; ++u) M2[u] = 0.0f;
  int js[8], qs[8];
#pragma unroll
  for (int r = 0; r < 8; ++r) {
    const int pix = tid + (r << 16);
    js[r] = idx[pix]; qs[r] = pix >> 5;
  }
#pragma unroll
  for (int r = 0; r < 8; ++r) {
    const int b = qs[r] >> 10;
    const float* xp = xyz    + (size_t)(b*N_ + js[r])*3;
    const float* pq = points + (size_t)(b*N_ + js[r])*3;
    const float* nq = nx + qs[r]*3;
    float g[6];
    g[0] = xp[0]-nq[0]; g[1] = xp[1]-nq[1]; g[2] = xp[2]-nq[2];
    g[3] = pq[0]; g[4] = pq[1]; g[5] = pq[2];
#pragma unroll
    for (int i = 0; i < 6; ++i) m[i] += g[i];
    int u = 0;
#pragma unroll
    for (int i = 0; i < 6; ++i)
#pragma unroll
      for (int jj = i; jj < 6; ++jj) { M2[u] = fmaf(g[i], g[jj], M2[u]); ++u; }
  }
#pragma unroll
  for (int i = 0; i < 6; ++i)
#pragma unroll
    for (int s = 1; s < 64; s <<= 1) m[i] += __shfl_xor(m[i], s);
#pragma unroll
  for (int u = 0; u < 21; ++u)
#pragma unroll
    for (int s = 1; s < 64; s <<= 1) M2[u] += __shfl_xor(M2[u], s);
  if ((threadIdx.x & 63) == 0) {
    const int w = blockIdx.x * 4 + (threadIdx.x >> 6);    // 1024 waves
    float* dst = momp + w*32;
#pragma unroll
    for (int i = 0; i < 6; ++i) dst[i] = m[i];
#pragma unroll
    for (int u = 0; u < 21; ++u) dst[6+u] = M2[u];
  }
}

// ---------------- BN0 finalize: reduce momp partials + closed-form stats ----------------
__global__ void k_fin0r(const float* __restrict__ momp,
                        const float* __restrict__ w0, const float* __restrict__ b0,
                        const float* __restrict__ g0, const float* __restrict__ be0,
                        float* __restrict__ pr) {
  __shared__ float part[8][32];
  __shared__ float red[32];
  const int t = threadIdx.x;          // 256
  const int c = t & 31, p = t >> 5;   // p < 8
  float a = 0.f;
  for (int w = p; w < 1024; w += 8) a += momp[w*32 + c];
  part[p][c] = a;
  __syncthreads();
  if (t < 32) {
    float s = 0.f;
#pragma unroll
    for (int pp = 0; pp < 8; ++pp) s += part[pp][c];
    red[c] = s;
  }
  __syncthreads();
  if (t < 64) {
    const float inv = 1.0f / (float)NPIX_;
    float m1[6];
#pragma unroll
    for (int i = 0; i < 6; ++i) m1[i] = red[i] * inv;
    float M2[6][6];
    int u = 0;
#pragma unroll
    for (int i = 0; i < 6; ++i)
#pragma unroll
      for (int jj = i; jj < 6; ++jj) { float v = red[6+u]*inv; M2[i][jj] = v; M2[jj][i] = v; ++u; }
    float w[6];
#pragma unroll
    for (int i = 0; i < 6; ++i) w[i] = w0[t*6+i];
    float ml = 0.0f;
#pragma unroll
    for (int i = 0; i < 6; ++i) ml += w[i]*m1[i];
    float e2 = 0.0f;
#pragma unroll
    for (int i = 0; i < 6; ++i)
#pragma unroll
      for (int jj = 0; jj < 6; ++jj) e2 += w[i]*w[jj]*M2[i][jj];
    const float var = e2 - ml*ml;
    const float mean = ml + b0[t];
    const float sc = g0[t] * rsqrtf(var + EPS_);
    pr[t] = sc; pr[64+t] = be0[t] - mean*sc;
  }
}

// ---------------- BN1 finalize: reduce s1p [4096 waves][32] ----------------
__global__ void k_fin1r(const float* __restrict__ s1p,
                        const float* __restrict__ g1, const float* __restrict__ be1,
                        float* __restrict__ pr) {
  __shared__ float pa[4][64], pb[4][64];
  const int t = threadIdx.x;          // 256
  const int c = t & 63, p = t >> 6;   // p < 4
  const int wq = c >> 4, u = c & 15;
  float sa = 0.f, sb = 0.f;
  for (int blk = p; blk < 1024; blk += 4) {
    const int w = blk*4 + wq;
    sa += s1p[w*32 + u];
    sb += s1p[w*32 + 16 + u];
  }
  pa[p][c] = sa; pb[p][c] = sb;
  __syncthreads();
  if (t < 64) {
    const float A  = pa[0][t]+pa[1][t]+pa[2][t]+pa[3][t];
    const float Bq = pb[0][t]+pb[1][t]+pb[2][t]+pb[3][t];
    const float inv = 1.0f / (float)NPIX_;
    const float mean = A*inv;
    const float var = Bq*inv - mean*mean;
    const float sc = g1[t] * rsqrtf(var + EPS_);
    pr[128+t] = sc; pr[192+t] = be1[t] - mean*sc;
  }
}

// ---------------- BN2 finalize: reduce s2p [4096 waves][64] ----------------
__global__ void k_fin2r(const float* __restrict__ s2p,
                        const float* __restrict__ g2, const float* __restrict__ be2,
                        float* __restrict__ pr) {
  __shared__ float pa[2][128], pb[2][128];
  const int t = threadIdx.x;            // 256
  const int c = t & 127, p = t >> 7;    // p < 2
  const int wq = c >> 5, u = c & 31;
  float sa = 0.f, sb = 0.f;
  for (int blk = p; blk < 1024; blk += 2) {
    const int w = blk*4 + wq;
    sa += s2p[w*64 + u];
    sb += s2p[w*64 + 32 + u];
  }
  pa[p][c] = sa; pb[p][c] = sb;
  __syncthreads();
  if (t < 128) {
    const float A  = pa[0][t]+pa[1][t];
    const float Bq = pb[0][t]+pb[1][t];
    const float inv = 1.0f / (float)NPIX_;
    const float mean = A*inv;
    const float var = Bq*inv - mean*mean;
    const float sc = g2[t] * rsqrtf(var + EPS_);
    pr[256+t] = sc; pr[384+t] = be2[t] - mean*sc;
  }
}

// ---------------- atomic finalizers (fallback path) ----------------
__global__ void k_mom(const float* __restrict__ xyz, const float* __restrict__ points,
                      const float* __restrict__ nx, const int* __restrict__ idx,
                      float* __restrict__ st) {
  const int tid = blockIdx.x * blockDim.x + threadIdx.x;
  float m[6] = {0,0,0,0,0,0};
  float M2[21];
#pragma unroll
  for (int u = 0; u < 21; ++u) M2[u] = 0.0f;
  int js[8], qs[8];
#pragma unroll
  for (int r = 0; r < 8; ++r) { const int pix = tid + (r << 16); js[r] = idx[pix]; qs[r] = pix >> 5; }
#pragma unroll
  for (int r = 0; r < 8; ++r) {
    const int b = qs[r] >> 10;
    const float* xp = xyz    + (size_t)(b*N_ + js[r])*3;
    const float* pq = points + (size_t)(b*N_ + js[r])*3;
    const float* nq = nx + qs[r]*3;
    float g[6];
    g[0] = xp[0]-nq[0]; g[1] = xp[1]-nq[1]; g[2] = xp[2]-nq[2];
    g[3] = pq[0]; g[4] = pq[1]; g[5] = pq[2];
#pragma unroll
    for (int i = 0; i < 6; ++i) m[i] += g[i];
    int u = 0;
#pragma unroll
    for (int i = 0; i < 6; ++i)
#pragma unroll
      for (int jj = i; jj < 6; ++jj) { M2[u] = fmaf(g[i], g[jj], M2[u]); ++u; }
  }
#pragma unroll
  for (int i = 0; i < 6; ++i)
#pragma unroll
    for (int s = 1; s < 64; s <<= 1) m[i] += __shfl_xor(m[i], s);
#pragma unroll
  for (int u = 0; u < 21; ++u)
#pragma unroll
    for (int s = 1; s < 64; s <<= 1) M2[u] += __shfl_xor(M2[u], s);
  if ((threadIdx.x & 63) == 0) {
#pragma unroll
    for (int i = 0; i < 6; ++i) atomicAdd(&st[i], m[i]);
#pragma unroll
    for (int u = 0; u < 21; ++u) atomicAdd(&st[6+u], M2[u]);
  }
}

__global__ void k_fin0(const float* __restrict__ w0, const float* __restrict__ b0,
                       const float* __restrict__ g0, const float* __restrict__ be0,
                       const float* __restrict__ st, float* __restrict__ pr) {
  const int c = threadIdx.x;
  const float inv = 1.0f / (float)NPIX_;
  float m1[6];
#pragma unroll
  for (int i = 0; i < 6; ++i) m1[i] = st[i] * inv;
  float M2[6][6];
  int u = 0;
#pragma unroll
  for (int i = 0; i < 6; ++i)
#pragma unroll
    for (int jj = i; jj < 6; ++jj) { float v = st[6+u]*inv; M2[i][jj] = v; M2[jj][i] = v; ++u; }
  float w[6];
#pragma unroll
  for (int i = 0; i < 6; ++i) w[i] = w0[c*6+i];
  float ml = 0.0f;
#pragma unroll
  for (int i = 0; i < 6; ++i) ml += w[i]*m1[i];
  float e2 = 0.0f;
#pragma unroll
  for (int i = 0; i < 6; ++i)
#pragma unroll
    for (int jj = 0; jj < 6; ++jj) e2 += w[i]*w[jj]*M2[i][jj];
  const float var = e2 - ml*ml;
  const float mean = ml + b0[c];
  const float sc = g0[c] * rsqrtf(var + EPS_);
  pr[c] = sc; pr[64+c] = be0[c] - mean*sc;
}

__global__ void k_fin(const float* __restrict__ gam, const float* __restrict__ bet,
                      const float* __restrict__ ssum, const float* __restrict__ ssq,
                      float* __restrict__ psc, float* __restrict__ psh) {
  const int c = threadIdx.x;
  const float inv = 1.0f / (float)NPIX_;
  const float mean = ssum[c]*inv;
  const float var = ssq[c]*inv - mean*mean;
  const float sc = gam[c] * rsqrtf(var + EPS_);
  psc[c] = sc; psh[c] = bet[c] - mean*sc;
}

// ---------------- BIG-WS PATH ----------------
// s1: gather(regs) -> l0 -> bn0relu -> LDS -> l1 -> partial stores + a1 fp16 pixel-major
__global__ __launch_bounds__(256) void k_s1(
    const float* __restrict__ xyz, const float* __restrict__ points,
    const float* __restrict__ nx, const int* __restrict__ idx,
    const float* __restrict__ w0t, const float* __restrict__ w1t,
    const float* __restrict__ b0, const float* __restrict__ b1,
    const float* __restrict__ pr, float* __restrict__ s1p,
    __half* __restrict__ a1)
{
  __shared__ float a0T[64][64];
  const int tid = threadIdx.x;
  const int lane = tid & 63;
  const int wid = __builtin_amdgcn_readfirstlane(tid >> 6);
  const int c0 = wid * 16;
  float b0r[16], b1r[16], p0s[16], p0h[16];
#pragma unroll
  for (int u = 0; u < 16; ++u) {
    b0r[u] = b0[c0+u]; b1r[u] = b1[c0+u];
    p0s[u] = pr[c0+u]; p0h[u] = pr[64+c0+u];
  }
  float s1a[16], s1b[16];
#pragma unroll
  for (int u = 0; u < 16; ++u) { s1a[u] = 0.0f; s1b[u] = 0.0f; }

  for (int tile = blockIdx.x; tile < NQ_/2; tile += gridDim.x) {
    const int q = tile*2 + (lane >> 5);
    const int k = lane & 31;
    const int b = q >> 10;
    const int j = idx[q*K_ + k];
    const float* xp = xyz    + (size_t)(b*N_ + j)*3;
    const float* pp = points + (size_t)(b*N_ + j)*3;
    const float* nq = nx + q*3;
    float g[6];
    g[0] = xp[0]-nq[0]; g[1] = xp[1]-nq[1]; g[2] = xp[2]-nq[2];
    g[3] = pp[0];       g[4] = pp[1];       g[5] = pp[2];
    float acc[16];
#pragma unroll
    for (int u = 0; u < 16; ++u) acc[u] = b0r[u];
#pragma unroll
    for (int i = 0; i < 6; ++i) {
      const float* w = w0t + i*64 + c0;
#pragma unroll
      for (int u = 0; u < 16; ++u) acc[u] = fmaf(w[u], g[i], acc[u]);
    }
#pragma unroll
    for (int u = 0; u < 16; ++u)
      a0T[c0+u][lane] = fmaxf(fmaf(p0s[u], acc[u], p0h[u]), 0.0f);
    __syncthreads();
#pragma unroll
    for (int u = 0; u < 16; ++u) acc[u] = b1r[u];
#pragma unroll 8
    for (int ci = 0; ci < 64; ++ci) {
      const float av = a0T[ci][lane];
      const float* w = w1t + ci*64 + c0;
#pragma unroll
      for (int u = 0; u < 16; ++u) acc[u] = fmaf(w[u], av, acc[u]);
    }
    const int pix = tile*64 + lane;
    __half hbuf[16];
#pragma unroll
    for (int u = 0; u < 16; ++u) {
      s1a[u] += acc[u]; s1b[u] = fmaf(acc[u], acc[u], s1b[u]);
      hbuf[u] = __float2half(acc[u]);
    }
    // pixel-major: 16 contiguous halves = 32 B per lane = 2x dwordx4
    float4* dst4 = (float4*)(a1 + (size_t)pix*64 + c0);
    dst4[0] = *(const float4*)&hbuf[0];
    dst4[1] = *(const float4*)&hbuf[8];
    __syncthreads();
  }
#pragma unroll
  for (int u = 0; u < 16; ++u) {
    float a = s1a[u], bq = s1b[u];
#pragma unroll
    for (int s = 1; s < 64; s <<= 1) { a += __shfl_xor(a, s); bq += __shfl_xor(bq, s); }
    s1a[u] = a; s1b[u] = bq;
  }
  if (lane == 0) {
    float* dst = s1p + (blockIdx.x*4 + wid)*32;
#pragma unroll
    for (int u = 0; u < 16; ++u) { dst[u] = s1a[u]; dst[16+u] = s1b[u]; }
  }
}

// s2: read a1 fp16 pixel-major (2x dwordx4/lane) -> bn1relu -> LDS transpose -> l2
//     -> partial stores + sign-aware k-maxpool (pre-BN2)
__global__ __launch_bounds__(256) void k_s2(
    const __half* __restrict__ a1, const float* __restrict__ w2t,
    const float* __restrict__ b2, const float* __restrict__ g2,
    const float* __restrict__ pr, float* __restrict__ s2p,
    float* __restrict__ pooled)
{
  __shared__ float a1T[64][64];
  const int tid = threadIdx.x;
  const int lane = tid & 63;
  const int wid = __builtin_amdgcn_readfirstlane(tid >> 6);
  const int cl = wid * 16;    // load channels
  const int c20 = wid * 32;   // output channels
  float p1s[16], p1h[16], b2r[32];
  bool g2p[32];
#pragma unroll
  for (int u = 0; u < 16; ++u) { p1s[u] = pr[128+cl+u]; p1h[u] = pr[192+cl+u]; }
#pragma unroll
  for (int u = 0; u < 32; ++u) { b2r[u] = b2[c20+u]; g2p[u] = (g2[c20+u] >= 0.0f); }
  float s2a[32], s2b[32];
#pragma unroll
  for (int u = 0; u < 32; ++u) { s2a[u] = 0.0f; s2b[u] = 0.0f; }

  for (int tile = blockIdx.x; tile < NQ_/2; tile += gridDim.x) {
    const int pix = tile*64 + lane;
    // pixel-major: lane loads its pixel's channels [cl, cl+16) = 32 B = 2x dwordx4
    const float4* src4 = (const float4*)(a1 + (size_t)pix*64 + cl);
    __half hbuf[16];
    *(float4*)&hbuf[0] = src4[0];
    *(float4*)&hbuf[8] = src4[1];
#pragma unroll
    for (int u = 0; u < 16; ++u) {
      const float v = __half2float(hbuf[u]);
      a1T[cl+u][lane] = fmaxf(fmaf(p1s[u], v, p1h[u]), 0.0f);
    }
    __syncthreads();
    float acc2[32];
#pragma unroll
    for (int u = 0; u < 32; ++u) acc2[u] = b2r[u];
#pragma unroll 8
    for (int ci = 0; ci < 64; ++ci) {
      const float av = a1T[ci][lane];
      const float* w = w2t + ci*128 + c20;
#pragma unroll
      for (int u = 0; u < 32; ++u) acc2[u] = fmaf(w[u], av, acc2[u]);
    }
    const int q = tile*2 + (lane >> 5);
#pragma unroll
    for (int u = 0; u < 32; ++u) {
      s2a[u] += acc2[u]; s2b[u] = fmaf(acc2[u], acc2[u], s2b[u]);
      float r = g2p[u] ? acc2[u] : -acc2[u];
      DPPMAXF(r, 0xB1);   // quad_perm [1,0,3,2]
      DPPMAXF(r, 0x4E);   // quad_perm [2,3,0,1]
      DPPMAXF(r, 0x141);  // row_half_mirror
      DPPMAXF(r, 0x140);  // row_mirror
      DPPMAXF(r, 0x142);  // row_bcast15
      if ((lane & 31) == 31) pooled[q*128 + c20 + u] = g2p[u] ? r : -r;
    }
    __syncthreads();
  }
#pragma unroll
  for (int u = 0; u < 32; ++u) {
    float a = s2a[u], bq = s2b[u];
#pragma unroll
    for (int s = 1; s < 64; s <<= 1) { a += __shfl_xor(a, s); bq += __shfl_xor(bq, s); }
    s2a[u] = a; s2b[u] = bq;
  }
  if (lane == 0) {
    float* dst = s2p + (blockIdx.x*4 + wid)*64;
#pragma unroll
    for (int u = 0; u < 32; ++u) { dst[u] = s2a[u]; dst[32+u] = s2b[u]; }
  }
}

// s3: in-place over out[OUTNP_..]: bn2 affine -> relu
__global__ __launch_bounds__(256) void k_s3(const float* __restrict__ pr,
                                            float* __restrict__ outnp) {
  const int g = blockIdx.x * 256 + threadIdx.x;
  const int c = g & 127;
  const float y = fmaf(pr[256+c], outnp[g], pr[384+c]);
  outnp[g] = fmaxf(y, 0.0f);
}

// ---------------- FALLBACK (small ws): fused recompute stages ----------------
template<int STAGE>
__global__ __launch_bounds__(256) void k_stage(
    const float* __restrict__ xyz, const float* __restrict__ points,
    const float* __restrict__ nx, const int* __restrict__ idx,
    const float* __restrict__ w0t, const float* __restrict__ w1t,
    const float* __restrict__ w2t,
    const float* __restrict__ b0, const float* __restrict__ b1,
    const float* __restrict__ b2,
    const float* __restrict__ pr, float* __restrict__ st,
    float* __restrict__ out)
{
  __shared__ float gT[6][64];
  __shared__ float a0T[64][64];
  __shared__ float a1T[64][64];
  const int tid = threadIdx.x;
  const int lane = tid & 63;
  const int wid = __builtin_amdgcn_readfirstlane(tid >> 6);
  const int c0 = wid * 16;
  const int c20 = wid * 32;

  float s1a[16], s1b[16], s2a[32], s2b[32];
  if (STAGE == 1) {
#pragma unroll
    for (int u = 0; u < 16; ++u) { s1a[u] = 0.0f; s1b[u] = 0.0f; }
  }
  if (STAGE == 2) {
#pragma unroll
    for (int u = 0; u < 32; ++u) { s2a[u] = 0.0f; s2b[u] = 0.0f; }
  }

  for (int tile = blockIdx.x; tile < NQ_/2; tile += gridDim.x) {
    const int q = tile*2 + (lane >> 5);
    const int k = lane & 31;
    if (wid == 0) {
      const int b = q >> 10;
      const int j = idx[q*K_ + k];
      const float* xp = xyz    + (size_t)(b*N_ + j)*3;
      const float* pp = points + (size_t)(b*N_ + j)*3;
      const float* nq = nx + q*3;
      gT[0][lane] = xp[0]-nq[0]; gT[1][lane] = xp[1]-nq[1]; gT[2][lane] = xp[2]-nq[2];
      gT[3][lane] = pp[0];       gT[4][lane] = pp[1];       gT[5][lane] = pp[2];
    }
    __syncthreads();
    float acc[16];
#pragma unroll
    for (int u = 0; u < 16; ++u) acc[u] = b0[c0+u];
#pragma unroll
    for (int i = 0; i < 6; ++i) {
      const float av = gT[i][lane];
      const float* w = w0t + i*64 + c0;
#pragma unroll
      for (int u = 0; u < 16; ++u) acc[u] = fmaf(w[u], av, acc[u]);
    }
#pragma unroll
    for (int u = 0; u < 16; ++u) {
      const float a = fmaf(pr[c0+u], acc[u], pr[64+c0+u]);
      a0T[c0+u][lane] = fmaxf(a, 0.0f);
    }
    __syncthreads();
#pragma unroll
    for (int u = 0; u < 16; ++u) acc[u] = b1[c0+u];
#pragma unroll 8
    for (int ci = 0; ci < 64; ++ci) {
      const float av = a0T[ci][lane];
      const float* w = w1t + ci*64 + c0;
#pragma unroll
      for (int u = 0; u < 16; ++u) acc[u] = fmaf(w[u], av, acc[u]);
    }
    if (STAGE == 1) {
#pragma unroll
      for (int u = 0; u < 16; ++u) { s1a[u] += acc[u]; s1b[u] = fmaf(acc[u], acc[u], s1b[u]); }
    } else {
#pragma unroll
      for (int u = 0; u < 16; ++u) {
        const float a = fmaf(pr[128+c0+u], acc[u], pr[192+c0+u]);
        a1T[c0+u][lane] = fmaxf(a, 0.0f);
      }
      __syncthreads();
      float acc2[32];
#pragma unroll
      for (int u = 0; u < 32; ++u) acc2[u] = b2[c20+u];
#pragma unroll 8
      for (int ci = 0; ci < 64; ++ci) {
        const float av = a1T[ci][lane];
        const float* w = w2t + ci*128 + c20;
#pragma unroll
        for (int u = 0; u < 32; ++u) acc2[u] = fmaf(w[u], av, acc2[u]);
      }
      if (STAGE == 2) {
#pragma unroll
        for (int u = 0; u < 32; ++u) { s2a[u] += acc2[u]; s2b[u] = fmaf(acc2[u], acc2[u], s2b[u]); }
      } else {
#pragma unroll
        for (int u = 0; u < 32; ++u) {
          float y = fmaf(pr[256+c20+u], acc2[u], pr[384+c20+u]);
#pragma unroll
          for (int s = 1; s < 32; s <<= 1) y = fmaxf(y, __shfl_xor(y, s));
          if ((lane & 31) == 0) out[OUTNP_ + q*128 + c20 + u] = fmaxf(y, 0.0f);
        }
      }
    }
    __syncthreads();
  }
  if (STAGE == 1) {
#pragma unroll
    for (int u = 0; u < 16; ++u) {
      float a = s1a[u], bq = s1b[u];
#pragma unroll
      for (int s = 1; s < 64; s <<= 1) { a += __shfl_xor(a, s); bq += __shfl_xor(bq, s); }
      if (lane == 0) { atomicAdd(&st[32 + c0+u], a); atomicAdd(&st[96 + c0+u], bq); }
    }
  }
  if (STAGE == 2) {
#pragma unroll
    for (int u = 0; u < 32; ++u) {
      float a = s2a[u], bq = s2b[u];
#pragma unroll
      for (int s = 1; s < 64; s <<= 1) { a += __shfl_xor(a, s); bq += __shfl_xor(bq, s); }
      if (lane == 0) { atomicAdd(&st[160 + c20+u], a); atomicAdd(&st[288 + c20+u], bq); }
    }
  }
}

extern "C" void kernel_launch(void* const* d_in, const int* in_sizes, int n_in,
                              void* d_out, int out_size, void* d_ws, size_t ws_size,
                              hipStream_t stream) {
  const float* xyz    = (const float*)d_in[0];
  const float* points = (const float*)d_in[1];
  const float* w0  = (const float*)d_in[2];
  const float* b0  = (const float*)d_in[3];
  const float* g0  = (const float*)d_in[4];
  const float* be0 = (const float*)d_in[5];
  const float* w1  = (const float*)d_in[6];
  const float* b1  = (const float*)d_in[7];
  const float* g1  = (const float*)d_in[8];
  const float* be1 = (const float*)d_in[9];
  const float* w2  = (const float*)d_in[10];
  const float* b2  = (const float*)d_in[11];
  const float* g2  = (const float*)d_in[12];
  const float* be2 = (const float*)d_in[13];
  float* out = (float*)d_out;
  float* ws  = (float*)d_ws;

  float* nx  = ws;                       // 49152
  int*   idx = (int*)(ws + 49152);       // 524288 ints
  float* w0t = ws + 573440;
  float* w1t = ws + 573824;
  float* w2t = ws + 577920;
  float* st  = ws + 586112;              // 512 floats (fallback)
  float* pr  = ws + 586624;              // 512 floats
  __half* a1 = (__half*)(ws + 2684928);  // 33554432 halfs (67MB), pixel-major [NPIX][64]
  float* momp = ws + 587264;             // 1024*32
  float* s1p  = ws + 587264 + 32768;     // 4096*32
  float* s2p  = (float*)(ws + 49152);    // 4096*64 aliases idx (dead after s1)
  float* pooled = out + OUTNP_;          // s2 writes pre-BN pooled into out; s3 finishes in place

  const size_t need = (size_t)(2684928) * sizeof(float) + (size_t)33554432 * sizeof(__half);
  const bool big = ws_size >= need;

  k_fps<<<B_, 512, 0, stream>>>(xyz, out, nx);
  k_ball<<<NQ_/4 + 1, 256, 0, stream>>>(xyz, nx, idx, w0, w1, w2, w0t, w1t, w2t);
  if (big) {
    k_momw<<<256, 256, 0, stream>>>(xyz, points, nx, idx, momp);
    k_fin0r<<<1, 256, 0, stream>>>(momp, w0, b0, g0, be0, pr);
    k_s1<<<1024, 256, 0, stream>>>(xyz, points, nx, idx, w0t, w1t, b0, b1, pr, s1p, a1);
    k_fin1r<<<1, 256, 0, stream>>>(s1p, g1, be1, pr);
    k_s2<<<1024, 256, 0, stream>>>(a1, w2t, b2, g2, pr, s2p, pooled);
    k_fin2r<<<1, 256, 0, stream>>>(s2p, g2, be2, pr);
    k_s3<<<NPIX_*4/256, 256, 0, stream>>>(pr, pooled);
  } else {
    hipMemsetAsync(st, 0, 512*sizeof(float), stream);
    k_mom<<<256, 256, 0, stream>>>(xyz, points, nx, idx, st);
    k_fin0<<<1, 64, 0, stream>>>(w0, b0, g0, be0, st, pr);
    k_stage<1><<<1024, 256, 0, stream>>>(xyz, points, nx, idx, w0t, w1t, w2t, b0, b1, b2, pr, st, out);
    k_fin<<<1, 64, 0, stream>>>(g1, be1, st+32, st+96, pr+128, pr+192);
    k_stage<2><<<1024, 256, 0, stream>>>(xyz, points, nx, idx, w0t, w1t, w2t, b0, b1, b2, pr, st, out);
    k_fin<<<1, 128, 0, stream>>>(g2, be2, st+160, st+288, pr+256, pr+384);
    k_stage<3><<<1024, 256, 0, stream>>>(xyz, points, nx, idx, w0t, w1t, w2t, b0, b1, b2, pr, st, out);
  }
}

// Round 13
// 1041.581 us; speedup vs baseline: 2.0140x; 1.1934x over previous
//
#include <hip/hip_runtime.h>
#include <hip/hip_fp16.h>
#include <stdint.h>

#define B_ 16
#define N_ 4096
#define S_ 1024
#define K_ 32
#define NQ_ (B_*S_)          // 16384
#define NPIX_ (NQ_*K_)       // 524288
#define OUTNP_ (NQ_*3)       // 49152 floats of new_xyz, then new_points
#define EPS_ 1e-5f
#define NBS_ 2048            // s1/s2 grid
#define NBM_ 1024            // momw grid

// ws layout (floats):
// [0, 49152)            new_xyz copy
// [49152, 573440)       idx (int32) NPIX_   [s2p (8192*64 f32 = 524288) aliases exactly after s1]
// [573440, 573824)      w0t  (6 x 64)
// [573824, 577920)      w1t  (64 x 64)
// [577920, 586112)      w2t  (64 x 128)
// [586112, 586624)      red0[32] (big path) / st (fallback)
// [586624, 587136)      pr: scale0[64] shift0[64] scale1[64] shift1[64] scale2[128] shift2[128]
// [587264, 718336)      momp (4096*32)
// [718336, 980480)      s1p (8192*32)
// [2684928, ...)        a1_pre fp16 pixel-major [NPIX][64] (67MB)

#define DPPMAX64(x, CTRL) do { \
  unsigned _lo = (unsigned)(x); unsigned _hi = (unsigned)((x)>>32); \
  unsigned _plo = (unsigned)__builtin_amdgcn_update_dpp((int)_lo,(int)_lo,(CTRL),0xF,0xF,false); \
  unsigned _phi = (unsigned)__builtin_amdgcn_update_dpp((int)_hi,(int)_hi,(CTRL),0xF,0xF,false); \
  unsigned long long _p = (((unsigned long long)_phi)<<32)|_plo; \
  if (_p > (x)) (x) = _p; \
} while(0)

#define DPPMAXF(r, CTRL) do { \
  float _t = __int_as_float(__builtin_amdgcn_update_dpp(__float_as_int(r),__float_as_int(r),(CTRL),0xF,0xF,false)); \
  (r) = fmaxf((r), _t); \
} while(0)

// ---------------- FPS (r8 frozen) ----------------
__global__ __launch_bounds__(512) void k_fps(const float* __restrict__ xyz,
                                             float* __restrict__ out,
                                             float* __restrict__ nx) {
  const int b = blockIdx.x;
  const int t = threadIdx.x;
  const int lane = t & 63, wid = t >> 6;
  __shared__ int SX[N_], SY[N_], SZ[N_];
  __shared__ unsigned long long kbuf[2][8];
  const float* xb = xyz + (size_t)b * N_ * 3;
  for (int j = t; j < N_; j += 512) {
    SX[j] = (int)(xb[j*3+0] * 536870912.0f);   // x*2^29, exact
    SY[j] = (int)(xb[j*3+1] * 536870912.0f);
    SZ[j] = (int)(xb[j*3+2] * 536870912.0f);
  }
  __syncthreads();
  int PX[8], PY[8], PZ[8];
  unsigned long long key[8];
#pragma unroll
  for (int i = 0; i < 8; ++i) {
    const int j = t*8 + i;
    PX[i] = SX[j]; PY[i] = SY[j]; PZ[i] = SZ[j];
    key[i] = ~0ull;
  }
  int far = 0, farA = 0, farB = 0;
  for (int it = 0; it < S_; ++it) {
    if (it == t)       farA = far;
    if (it == t + 512) farB = far;
    if (it == S_-1) break;
    const int cx = SX[far], cy = SY[far], cz = SZ[far];
    unsigned long long best = 0;
#pragma unroll
    for (int i = 0; i < 8; ++i) {
      const int dx = PX[i]-cx, dy = PY[i]-cy, dz = PZ[i]-cz;
      unsigned long long nk = (unsigned long long)(unsigned)(4095 - (t*8 + i));
      nk += (unsigned long long)((long long)dx*dx);
      nk += (unsigned long long)((long long)dy*dy);
      nk += (unsigned long long)((long long)dz*dz);
      if (nk < key[i]) key[i] = nk;
      if (key[i] > best) best = key[i];
    }
    DPPMAX64(best, 0x111);
    DPPMAX64(best, 0x112);
    DPPMAX64(best, 0x114);
    DPPMAX64(best, 0x118);
    DPPMAX64(best, 0x142);
    DPPMAX64(best, 0x143);
    if (lane == 63) kbuf[it & 1][wid] = best;
    __syncthreads();
    unsigned long long g = kbuf[it & 1][lane & 7];
    DPPMAX64(g, 0x111); DPPMAX64(g, 0x112); DPPMAX64(g, 0x114);
    far = 4095 - (__builtin_amdgcn_readlane((int)(unsigned)g, 7) & 4095);
  }
  {
    const float s = 1.862645149230957e-9f;
    const float ax = (float)SX[farA]*s, ay = (float)SY[farA]*s, az = (float)SZ[farA]*s;
    const float bx = (float)SX[farB]*s, by = (float)SY[farB]*s, bz = (float)SZ[farB]*s;
    const int oA = (b*S_ + t)*3;
    const int oB = (b*S_ + t + 512)*3;
    out[oA] = ax; out[oA+1] = ay; out[oA+2] = az;
    nx[oA]  = ax; nx[oA+1]  = ay; nx[oA+2]  = az;
    out[oB] = bx; out[oB+1] = by; out[oB+2] = bz;
    nx[oB]  = bx; nx[oB+1]  = by; nx[oB+2]  = bz;
  }
}

// ---------------- Ball query (+ merged weight-transpose prep block) ----------------
__global__ __launch_bounds__(256) void k_ball(const float* __restrict__ xyz,
                                              const float* __restrict__ nx,
                                              int* __restrict__ idx,
                                              const float* __restrict__ w0,
                                              const float* __restrict__ w1,
                                              const float* __restrict__ w2,
                                              float* __restrict__ w0t,
                                              float* __restrict__ w1t,
                                              float* __restrict__ w2t) {
  if (blockIdx.x == NQ_/4) {   // prep block
    const int t = threadIdx.x;
    for (int i = t; i < 64*6; i += 256)  { int o = i/6,  c = i%6;  w0t[c*64  + o] = w0[i]; }
    for (int i = t; i < 64*64; i += 256) { int o = i>>6, c = i&63; w1t[c*64  + o] = w1[i]; }
    for (int i = t; i < 128*64; i += 256){ int o = i>>6, c = i&63; w2t[c*128 + o] = w2[i]; }
    return;
  }
  const int lane = threadIdx.x & 63;
  const int q = blockIdx.x * 4 + (threadIdx.x >> 6);
  const int b = q >> 10;
  const float* xb = xyz + (size_t)b * N_ * 3;
  const double qx = (double)nx[q*3+0], qy = (double)nx[q*3+1], qz = (double)nx[q*3+2];
  const double qq = qx*qx + qy*qy + qz*qz;
  const double r2 = 0.2 * 0.2;
  int found = 0, first_j = 0;
  bool have_first = false;
  for (int c = 0; c < N_/64; ++c) {
    const int j = c*64 + lane;
    const double px = (double)xb[j*3+0], py = (double)xb[j*3+1], pz = (double)xb[j*3+2];
    const double dot = px*qx + py*qy + pz*qz;
    const double pp  = px*px + py*py + pz*pz;
    const double d   = qq + pp - 2.0*dot;
    const bool hit = (d <= r2);
    const unsigned long long mask = __ballot(hit);
    if (!have_first && mask) { first_j = c*64 + (__ffsll(mask) - 1); have_first = true; }
    const int pos = found + (int)__popcll(mask & ((1ull << lane) - 1ull));
    if (hit && pos < K_) idx[q*K_ + pos] = j;
    found += (int)__popcll(mask);
    if (found >= K_) break;
  }
  const int cnt = found < K_ ? found : K_;
  if (lane >= cnt && lane < K_) idx[q*K_ + lane] = first_j;
}

// ---------------- Moments: 1024 blocks (2 px/thread), per-wave partial stores ----------------
__global__ __launch_bounds__(256) void k_momw(const float* __restrict__ xyz,
                                              const float* __restrict__ points,
                                              const float* __restrict__ nx,
                                              const int* __restrict__ idx,
                                              float* __restrict__ momp) {
  const int tid = blockIdx.x * blockDim.x + threadIdx.x;   // 262144 threads, 2 px each
  float m[6] = {0,0,0,0,0,0};
  float M2[21];
#pragma unroll
  for (int u = 0; u < 21; ++u) M2[u] = 0.0f;
  int js[2], qs[2];
#pragma unroll
  for (int r = 0; r < 2; ++r) {
    const int pix = tid + (r << 18);
    js[r] = idx[pix]; qs[r] = pix >> 5;
  }
#pragma unroll
  for (int r = 0; r < 2; ++r) {
    const int b = qs[r] >> 10;
    const float* xp = xyz    + (size_t)(b*N_ + js[r])*3;
    const float* pq = points + (size_t)(b*N_ + js[r])*3;
    const float* nq = nx + qs[r]*3;
    float g[6];
    g[0] = xp[0]-nq[0]; g[1] = xp[1]-nq[1]; g[2] = xp[2]-nq[2];
    g[3] = pq[0]; g[4] = pq[1]; g[5] = pq[2];
#pragma unroll
    for (int i = 0; i < 6; ++i) m[i] += g[i];
    int u = 0;
#pragma unroll
    for (int i = 0; i < 6; ++i)
#pragma unroll
      for (int jj = i; jj < 6; ++jj) { M2[u] = fmaf(g[i], g[jj], M2[u]); ++u; }
  }
#pragma unroll
  for (int i = 0; i < 6; ++i)
#pragma unroll
    for (int s = 1; s < 64; s <<= 1) m[i] += __shfl_xor(m[i], s);
#pragma unroll
  for (int u = 0; u < 21; ++u)
#pragma unroll
    for (int s = 1; s < 64; s <<= 1) M2[u] += __shfl_xor(M2[u], s);
  if ((threadIdx.x & 63) == 0) {
    const int w = blockIdx.x * 4 + (threadIdx.x >> 6);    // 4096 waves
    float* dst = momp + w*32;
#pragma unroll
    for (int i = 0; i < 6; ++i) dst[i] = m[i];
#pragma unroll
    for (int u = 0; u < 21; ++u) dst[6+u] = M2[u];
  }
}

// ---------------- red0: 32 blocks, one moment index each ----------------
__global__ __launch_bounds__(256) void k_red0(const float* __restrict__ momp,
                                              float* __restrict__ red0) {
  __shared__ float red[256];
  const int c = blockIdx.x;
  const int t = threadIdx.x;
  float a = 0.f;
  for (int w = t; w < 4096; w += 256) a += momp[w*32 + c];
  red[t] = a;
  __syncthreads();
  for (int s = 128; s > 0; s >>= 1) {
    if (t < s) red[t] += red[t + s];
    __syncthreads();
  }
  if (t == 0) red0[c] = red[0];
}

// ---------------- fin0b: closed-form BN0 params from red0 ----------------
__global__ void k_fin0b(const float* __restrict__ red0,
                        const float* __restrict__ w0, const float* __restrict__ b0,
                        const float* __restrict__ g0, const float* __restrict__ be0,
                        float* __restrict__ pr) {
  __shared__ float red[32];
  const int t = threadIdx.x;   // 64
  if (t < 32) red[t] = red0[t];
  __syncthreads();
  const float inv = 1.0f / (float)NPIX_;
  float m1[6];
#pragma unroll
  for (int i = 0; i < 6; ++i) m1[i] = red[i] * inv;
  float M2[6][6];
  int u = 0;
#pragma unroll
  for (int i = 0; i < 6; ++i)
#pragma unroll
    for (int jj = i; jj < 6; ++jj) { float v = red[6+u]*inv; M2[i][jj] = v; M2[jj][i] = v; ++u; }
  float w[6];
#pragma unroll
  for (int i = 0; i < 6; ++i) w[i] = w0[t*6+i];
  float ml = 0.0f;
#pragma unroll
  for (int i = 0; i < 6; ++i) ml += w[i]*m1[i];
  float e2 = 0.0f;
#pragma unroll
  for (int i = 0; i < 6; ++i)
#pragma unroll
    for (int jj = 0; jj < 6; ++jj) e2 += w[i]*w[jj]*M2[i][jj];
  const float var = e2 - ml*ml;
  const float mean = ml + b0[t];
  const float sc = g0[t] * rsqrtf(var + EPS_);
  pr[t] = sc; pr[64+t] = be0[t] - mean*sc;
}

// ---------------- fin1c: 64 blocks, one channel each; reduce s1p[8192][32] ----------------
__global__ __launch_bounds__(256) void k_fin1c(const float* __restrict__ s1p,
                                               const float* __restrict__ g1,
                                               const float* __restrict__ be1,
                                               float* __restrict__ pr) {
  __shared__ float ra[256], rb[256];
  const int c = blockIdx.x;          // 0..63
  const int t = threadIdx.x;
  const int wid = c >> 4, u = c & 15;
  float sa = 0.f, sb = 0.f;
  for (int blk = t; blk < NBS_; blk += 256) {
    const int w = blk*4 + wid;
    sa += s1p[w*32 + u];
    sb += s1p[w*32 + 16 + u];
  }
  ra[t] = sa; rb[t] = sb;
  __syncthreads();
  for (int s = 128; s > 0; s >>= 1) {
    if (t < s) { ra[t] += ra[t + s]; rb[t] += rb[t + s]; }
    __syncthreads();
  }
  if (t == 0) {
    const float inv = 1.0f / (float)NPIX_;
    const float mean = ra[0]*inv;
    const float var = rb[0]*inv - mean*mean;
    const float sc = g1[c] * rsqrtf(var + EPS_);
    pr[128+c] = sc; pr[192+c] = be1[c] - mean*sc;
  }
}

// ---------------- fin2c: 128 blocks, one channel each; reduce s2p[8192][64] ----------------
__global__ __launch_bounds__(256) void k_fin2c(const float* __restrict__ s2p,
                                               const float* __restrict__ g2,
                                               const float* __restrict__ be2,
                                               float* __restrict__ pr) {
  __shared__ float ra[256], rb[256];
  const int c = blockIdx.x;          // 0..127
  const int t = threadIdx.x;
  const int wid = c >> 5, u = c & 31;
  float sa = 0.f, sb = 0.f;
  for (int blk = t; blk < NBS_; blk += 256) {
    const int w = blk*4 + wid;
    sa += s2p[w*64 + u];
    sb += s2p[w*64 + 32 + u];
  }
  ra[t] = sa; rb[t] = sb;
  __syncthreads();
  for (int s = 128; s > 0; s >>= 1) {
    if (t < s) { ra[t] += ra[t + s]; rb[t] += rb[t + s]; }
    __syncthreads();
  }
  if (t == 0) {
    const float inv = 1.0f / (float)NPIX_;
    const float mean = ra[0]*inv;
    const float var = rb[0]*inv - mean*mean;
    const float sc = g2[c] * rsqrtf(var + EPS_);
    pr[256+c] = sc; pr[384+c] = be2[c] - mean*sc;
  }
}

// ---------------- atomic finalizers (fallback path only) ----------------
__global__ void k_mom(const float* __restrict__ xyz, const float* __restrict__ points,
                      const float* __restrict__ nx, const int* __restrict__ idx,
                      float* __restrict__ st) {
  const int tid = blockIdx.x * blockDim.x + threadIdx.x;
  float m[6] = {0,0,0,0,0,0};
  float M2[21];
#pragma unroll
  for (int u = 0; u < 21; ++u) M2[u] = 0.0f;
  int js[8], qs[8];
#pragma unroll
  for (int r = 0; r < 8; ++r) { const int pix = tid + (r << 16); js[r] = idx[pix]; qs[r] = pix >> 5; }
#pragma unroll
  for (int r = 0; r < 8; ++r) {
    const int b = qs[r] >> 10;
    const float* xp = xyz    + (size_t)(b*N_ + js[r])*3;
    const float* pq = points + (size_t)(b*N_ + js[r])*3;
    const float* nq = nx + qs[r]*3;
    float g[6];
    g[0] = xp[0]-nq[0]; g[1] = xp[1]-nq[1]; g[2] = xp[2]-nq[2];
    g[3] = pq[0]; g[4] = pq[1]; g[5] = pq[2];
#pragma unroll
    for (int i = 0; i < 6; ++i) m[i] += g[i];
    int u = 0;
#pragma unroll
    for (int i = 0; i < 6; ++i)
#pragma unroll
      for (int jj = i; jj < 6; ++jj) { M2[u] = fmaf(g[i], g[jj], M2[u]); ++u; }
  }
#pragma unroll
  for (int i = 0; i < 6; ++i)
#pragma unroll
    for (int s = 1; s < 64; s <<= 1) m[i] += __shfl_xor(m[i], s);
#pragma unroll
  for (int u = 0; u < 21; ++u)
#pragma unroll
    for (int s = 1; s < 64; s <<= 1) M2[u] += __shfl_xor(M2[u], s);
  if ((threadIdx.x & 63) == 0) {
#pragma unroll
    for (int i = 0; i < 6; ++i) atomicAdd(&st[i], m[i]);
#pragma unroll
    for (int u = 0; u < 21; ++u) atomicAdd(&st[6+u], M2[u]);
  }
}

__global__ void k_fin0(const float* __restrict__ w0, const float* __restrict__ b0,
                       const float* __restrict__ g0, const float* __restrict__ be0,
                       const float* __restrict__ st, float* __restrict__ pr) {
  const int c = threadIdx.x;
  const float inv = 1.0f / (float)NPIX_;
  float m1[6];
#pragma unroll
  for (int i = 0; i < 6; ++i) m1[i] = st[i] * inv;
  float M2[6][6];
  int u = 0;
#pragma unroll
  for (int i = 0; i < 6; ++i)
#pragma unroll
    for (int jj = i; jj < 6; ++jj) { float v = st[6+u]*inv; M2[i][jj] = v; M2[jj][i] = v; ++u; }
  float w[6];
#pragma unroll
  for (int i = 0; i < 6; ++i) w[i] = w0[c*6+i];
  float ml = 0.0f;
#pragma unroll
  for (int i = 0; i < 6; ++i) ml += w[i]*m1[i];
  float e2 = 0.0f;
#pragma unroll
  for (int i = 0; i < 6; ++i)
#pragma unroll
    for (int jj = 0; jj < 6; ++jj) e2 += w[i]*w[jj]*M2[i][jj];
  const float var = e2 - ml*ml;
  const float mean = ml + b0[c];
  const float sc = g0[c] * rsqrtf(var + EPS_);
  pr[c] = sc; pr[64+c] = be0[c] - mean*sc;
}

__global__ void k_fin(const float* __restrict__ gam, const float* __restrict__ bet,
                      const float* __restrict__ ssum, const float* __restrict__ ssq,
                      float* __restrict__ psc, float* __restrict__ psh) {
  const int c = threadIdx.x;
  const float inv = 1.0f / (float)NPIX_;
  const float mean = ssum[c]*inv;
  const float var = ssq[c]*inv - mean*mean;
  const float sc = gam[c] * rsqrtf(var + EPS_);
  psc[c] = sc; psh[c] = bet[c] - mean*sc;
}

// ---------------- BIG-WS PATH ----------------
// s1: gather(regs) -> l0 -> bn0relu -> LDS -> l1 -> partial stores + a1 fp16 pixel-major
__global__ __launch_bounds__(256) void k_s1(
    const float* __restrict__ xyz, const float* __restrict__ points,
    const float* __restrict__ nx, const int* __restrict__ idx,
    const float* __restrict__ w0t, const float* __restrict__ w1t,
    const float* __restrict__ b0, const float* __restrict__ b1,
    const float* __restrict__ pr, float* __restrict__ s1p,
    __half* __restrict__ a1)
{
  __shared__ float a0T[64][64];
  const int tid = threadIdx.x;
  const int lane = tid & 63;
  const int wid = __builtin_amdgcn_readfirstlane(tid >> 6);
  const int c0 = wid * 16;
  float b0r[16], b1r[16], p0s[16], p0h[16];
#pragma unroll
  for (int u = 0; u < 16; ++u) {
    b0r[u] = b0[c0+u]; b1r[u] = b1[c0+u];
    p0s[u] = pr[c0+u]; p0h[u] = pr[64+c0+u];
  }
  float s1a[16], s1b[16];
#pragma unroll
  for (int u = 0; u < 16; ++u) { s1a[u] = 0.0f; s1b[u] = 0.0f; }

  for (int tile = blockIdx.x; tile < NQ_/2; tile += gridDim.x) {
    const int q = tile*2 + (lane >> 5);
    const int k = lane & 31;
    const int b = q >> 10;
    const int j = idx[q*K_ + k];
    const float* xp = xyz    + (size_t)(b*N_ + j)*3;
    const float* pp = points + (size_t)(b*N_ + j)*3;
    const float* nq = nx + q*3;
    float g[6];
    g[0] = xp[0]-nq[0]; g[1] = xp[1]-nq[1]; g[2] = xp[2]-nq[2];
    g[3] = pp[0];       g[4] = pp[1];       g[5] = pp[2];
    float acc[16];
#pragma unroll
    for (int u = 0; u < 16; ++u) acc[u] = b0r[u];
#pragma unroll
    for (int i = 0; i < 6; ++i) {
      const float* w = w0t + i*64 + c0;
#pragma unroll
      for (int u = 0; u < 16; ++u) acc[u] = fmaf(w[u], g[i], acc[u]);
    }
#pragma unroll
    for (int u = 0; u < 16; ++u)
      a0T[c0+u][lane] = fmaxf(fmaf(p0s[u], acc[u], p0h[u]), 0.0f);
    __syncthreads();
#pragma unroll
    for (int u = 0; u < 16; ++u) acc[u] = b1r[u];
#pragma unroll 8
    for (int ci = 0; ci < 64; ++ci) {
      const float av = a0T[ci][lane];
      const float* w = w1t + ci*64 + c0;
#pragma unroll
      for (int u = 0; u < 16; ++u) acc[u] = fmaf(w[u], av, acc[u]);
    }
    const int pix = tile*64 + lane;
    __half hbuf[16];
#pragma unroll
    for (int u = 0; u < 16; ++u) {
      s1a[u] += acc[u]; s1b[u] = fmaf(acc[u], acc[u], s1b[u]);
      hbuf[u] = __float2half(acc[u]);
    }
    float4* dst4 = (float4*)(a1 + (size_t)pix*64 + c0);
    dst4[0] = *(const float4*)&hbuf[0];
    dst4[1] = *(const float4*)&hbuf[8];
    __syncthreads();
  }
#pragma unroll
  for (int u = 0; u < 16; ++u) {
    float a = s1a[u], bq = s1b[u];
#pragma unroll
    for (int s = 1; s < 64; s <<= 1) { a += __shfl_xor(a, s); bq += __shfl_xor(bq, s); }
    s1a[u] = a; s1b[u] = bq;
  }
  if (lane == 0) {
    float* dst = s1p + (blockIdx.x*4 + wid)*32;
#pragma unroll
    for (int u = 0; u < 16; ++u) { dst[u] = s1a[u]; dst[16+u] = s1b[u]; }
  }
}

// s2: a1 fp16 pixel-major -> bn1relu -> LDS transpose -> l2 -> partials + pooled
__global__ __launch_bounds__(256) void k_s2(
    const __half* __restrict__ a1, const float* __restrict__ w2t,
    const float* __restrict__ b2, const float* __restrict__ g2,
    const float* __restrict__ pr, float* __restrict__ s2p,
    float* __restrict__ pooled)
{
  __shared__ float a1T[64][64];
  const int tid = threadIdx.x;
  const int lane = tid & 63;
  const int wid = __builtin_amdgcn_readfirstlane(tid >> 6);
  const int cl = wid * 16;
  const int c20 = wid * 32;
  float p1s[16], p1h[16], b2r[32];
  bool g2p[32];
#pragma unroll
  for (int u = 0; u < 16; ++u) { p1s[u] = pr[128+cl+u]; p1h[u] = pr[192+cl+u]; }
#pragma unroll
  for (int u = 0; u < 32; ++u) { b2r[u] = b2[c20+u]; g2p[u] = (g2[c20+u] >= 0.0f); }
  float s2a[32], s2b[32];
#pragma unroll
  for (int u = 0; u < 32; ++u) { s2a[u] = 0.0f; s2b[u] = 0.0f; }

  for (int tile = blockIdx.x; tile < NQ_/2; tile += gridDim.x) {
    const int pix = tile*64 + lane;
    const float4* src4 = (const float4*)(a1 + (size_t)pix*64 + cl);
    __half hbuf[16];
    *(float4*)&hbuf[0] = src4[0];
    *(float4*)&hbuf[8] = src4[1];
#pragma unroll
    for (int u = 0; u < 16; ++u) {
      const float v = __half2float(hbuf[u]);
      a1T[cl+u][lane] = fmaxf(fmaf(p1s[u], v, p1h[u]), 0.0f);
    }
    __syncthreads();
    float acc2[32];
#pragma unroll
    for (int u = 0; u < 32; ++u) acc2[u] = b2r[u];
#pragma unroll 8
    for (int ci = 0; ci < 64; ++ci) {
      const float av = a1T[ci][lane];
      const float* w = w2t + ci*128 + c20;
#pragma unroll
      for (int u = 0; u < 32; ++u) acc2[u] = fmaf(w[u], av, acc2[u]);
    }
    const int q = tile*2 + (lane >> 5);
#pragma unroll
    for (int u = 0; u < 32; ++u) {
      s2a[u] += acc2[u]; s2b[u] = fmaf(acc2[u], acc2[u], s2b[u]);
      float r = g2p[u] ? acc2[u] : -acc2[u];
      DPPMAXF(r, 0xB1);
      DPPMAXF(r, 0x4E);
      DPPMAXF(r, 0x141);
      DPPMAXF(r, 0x140);
      DPPMAXF(r, 0x142);
      if ((lane & 31) == 31) pooled[q*128 + c20 + u] = g2p[u] ? r : -r;
    }
    __syncthreads();
  }
#pragma unroll
  for (int u = 0; u < 32; ++u) {
    float a = s2a[u], bq = s2b[u];
#pragma unroll
    for (int s = 1; s < 64; s <<= 1) { a += __shfl_xor(a, s); bq += __shfl_xor(bq, s); }
    s2a[u] = a; s2b[u] = bq;
  }
  if (lane == 0) {
    float* dst = s2p + (blockIdx.x*4 + wid)*64;
#pragma unroll
    for (int u = 0; u < 32; ++u) { dst[u] = s2a[u]; dst[32+u] = s2b[u]; }
  }
}

// s3: in-place over out[OUTNP_..]: bn2 affine -> relu
__global__ __launch_bounds__(256) void k_s3(const float* __restrict__ pr,
                                            float* __restrict__ outnp) {
  const int g = blockIdx.x * 256 + threadIdx.x;
  const int c = g & 127;
  const float y = fmaf(pr[256+c], outnp[g], pr[384+c]);
  outnp[g] = fmaxf(y, 0.0f);
}

// ---------------- FALLBACK (small ws): fused recompute stages ----------------
template<int STAGE>
__global__ __launch_bounds__(256) void k_stage(
    const float* __restrict__ xyz, const float* __restrict__ points,
    const float* __restrict__ nx, const int* __restrict__ idx,
    const float* __restrict__ w0t, const float* __restrict__ w1t,
    const float* __restrict__ w2t,
    const float* __restrict__ b0, const float* __restrict__ b1,
    const float* __restrict__ b2,
    const float* __restrict__ pr, float* __restrict__ st,
    float* __restrict__ out)
{
  __shared__ float gT[6][64];
  __shared__ float a0T[64][64];
  __shared__ float a1T[64][64];
  const int tid = threadIdx.x;
  const int lane = tid & 63;
  const int wid = __builtin_amdgcn_readfirstlane(tid >> 6);
  const int c0 = wid * 16;
  const int c20 = wid * 32;

  float s1a[16], s1b[16], s2a[32], s2b[32];
  if (STAGE == 1) {
#pragma unroll
    for (int u = 0; u < 16; ++u) { s1a[u] = 0.0f; s1b[u] = 0.0f; }
  }
  if (STAGE == 2) {
#pragma unroll
    for (int u = 0; u < 32; ++u) { s2a[u] = 0.0f; s2b[u] = 0.0f; }
  }

  for (int tile = blockIdx.x; tile < NQ_/2; tile += gridDim.x) {
    const int q = tile*2 + (lane >> 5);
    const int k = lane & 31;
    if (wid == 0) {
      const int b = q >> 10;
      const int j = idx[q*K_ + k];
      const float* xp = xyz    + (size_t)(b*N_ + j)*3;
      const float* pp = points + (size_t)(b*N_ + j)*3;
      const float* nq = nx + q*3;
      gT[0][lane] = xp[0]-nq[0]; gT[1][lane] = xp[1]-nq[1]; gT[2][lane] = xp[2]-nq[2];
      gT[3][lane] = pp[0];       gT[4][lane] = pp[1];       gT[5][lane] = pp[2];
    }
    __syncthreads();
    float acc[16];
#pragma unroll
    for (int u = 0; u < 16; ++u) acc[u] = b0[c0+u];
#pragma unroll
    for (int i = 0; i < 6; ++i) {
      const float av = gT[i][lane];
      const float* w = w0t + i*64 + c0;
#pragma unroll
      for (int u = 0; u < 16; ++u) acc[u] = fmaf(w[u], av, acc[u]);
    }
#pragma unroll
    for (int u = 0; u < 16; ++u) {
      const float a = fmaf(pr[c0+u], acc[u], pr[64+c0+u]);
      a0T[c0+u][lane] = fmaxf(a, 0.0f);
    }
    __syncthreads();
#pragma unroll
    for (int u = 0; u < 16; ++u) acc[u] = b1[c0+u];
#pragma unroll 8
    for (int ci = 0; ci < 64; ++ci) {
      const float av = a0T[ci][lane];
      const float* w = w1t + ci*64 + c0;
#pragma unroll
      for (int u = 0; u < 16; ++u) acc[u] = fmaf(w[u], av, acc[u]);
    }
    if (STAGE == 1) {
#pragma unroll
      for (int u = 0; u < 16; ++u) { s1a[u] += acc[u]; s1b[u] = fmaf(acc[u], acc[u], s1b[u]); }
    } else {
#pragma unroll
      for (int u = 0; u < 16; ++u) {
        const float a = fmaf(pr[128+c0+u], acc[u], pr[192+c0+u]);
        a1T[c0+u][lane] = fmaxf(a, 0.0f);
      }
      __syncthreads();
      float acc2[32];
#pragma unroll
      for (int u = 0; u < 32; ++u) acc2[u] = b2[c20+u];
#pragma unroll 8
      for (int ci = 0; ci < 64; ++ci) {
        const float av = a1T[ci][lane];
        const float* w = w2t + ci*128 + c20;
#pragma unroll
        for (int u = 0; u < 32; ++u) acc2[u] = fmaf(w[u], av, acc2[u]);
      }
      if (STAGE == 2) {
#pragma unroll
        for (int u = 0; u < 32; ++u) { s2a[u] += acc2[u]; s2b[u] = fmaf(acc2[u], acc2[u], s2b[u]); }
      } else {
#pragma unroll
        for (int u = 0; u < 32; ++u) {
          float y = fmaf(pr[256+c20+u], acc2[u], pr[384+c20+u]);
#pragma unroll
          for (int s = 1; s < 32; s <<= 1) y = fmaxf(y, __shfl_xor(y, s));
          if ((lane & 31) == 0) out[OUTNP_ + q*128 + c20 + u] = fmaxf(y, 0.0f);
        }
      }
    }
    __syncthreads();
  }
  if (STAGE == 1) {
#pragma unroll
    for (int u = 0; u < 16; ++u) {
      float a = s1a[u], bq = s1b[u];
#pragma unroll
      for (int s = 1; s < 64; s <<= 1) { a += __shfl_xor(a, s); bq += __shfl_xor(bq, s); }
      if (lane == 0) { atomicAdd(&st[32 + c0+u], a); atomicAdd(&st[96 + c0+u], bq); }
    }
  }
  if (STAGE == 2) {
#pragma unroll
    for (int u = 0; u < 32; ++u) {
      float a = s2a[u], bq = s2b[u];
#pragma unroll
      for (int s = 1; s < 64; s <<= 1) { a += __shfl_xor(a, s); bq += __shfl_xor(bq, s); }
      if (lane == 0) { atomicAdd(&st[160 + c20+u], a); atomicAdd(&st[288 + c20+u], bq); }
    }
  }
}

extern "C" void kernel_launch(void* const* d_in, const int* in_sizes, int n_in,
                              void* d_out, int out_size, void* d_ws, size_t ws_size,
                              hipStream_t stream) {
  const float* xyz    = (const float*)d_in[0];
  const float* points = (const float*)d_in[1];
  const float* w0  = (const float*)d_in[2];
  const float* b0  = (const float*)d_in[3];
  const float* g0  = (const float*)d_in[4];
  const float* be0 = (const float*)d_in[5];
  const float* w1  = (const float*)d_in[6];
  const float* b1  = (const float*)d_in[7];
  const float* g1  = (const float*)d_in[8];
  const float* be1 = (const float*)d_in[9];
  const float* w2  = (const float*)d_in[10];
  const float* b2  = (const float*)d_in[11];
  const float* g2  = (const float*)d_in[12];
  const float* be2 = (const float*)d_in[13];
  float* out = (float*)d_out;
  float* ws  = (float*)d_ws;

  float* nx  = ws;                       // 49152
  int*   idx = (int*)(ws + 49152);       // 524288 ints
  float* w0t = ws + 573440;
  float* w1t = ws + 573824;
  float* w2t = ws + 577920;
  float* st  = ws + 586112;              // 512 floats (fallback) / red0 (big)
  float* red0 = ws + 586112;
  float* pr  = ws + 586624;              // 512 floats
  __half* a1 = (__half*)(ws + 2684928);  // 33554432 halfs (67MB), pixel-major [NPIX][64]
  float* momp = ws + 587264;             // 4096*32 = 131072
  float* s1p  = ws + 718336;             // 8192*32 = 262144 (ends 980480)
  float* s2p  = (float*)(ws + 49152);    // 8192*64 = 524288, aliases idx exactly (dead after s1)
  float* pooled = out + OUTNP_;          // s2 writes pre-BN pooled; s3 finishes in place

  const size_t need = (size_t)(2684928) * sizeof(float) + (size_t)33554432 * sizeof(__half);
  const bool big = ws_size >= need;

  k_fps<<<B_, 512, 0, stream>>>(xyz, out, nx);
  k_ball<<<NQ_/4 + 1, 256, 0, stream>>>(xyz, nx, idx, w0, w1, w2, w0t, w1t, w2t);
  if (big) {
    k_momw<<<NBM_, 256, 0, stream>>>(xyz, points, nx, idx, momp);
    k_red0<<<32, 256, 0, stream>>>(momp, red0);
    k_fin0b<<<1, 64, 0, stream>>>(red0, w0, b0, g0, be0, pr);
    k_s1<<<NBS_, 256, 0, stream>>>(xyz, points, nx, idx, w0t, w1t, b0, b1, pr, s1p, a1);
    k_fin1c<<<64, 256, 0, stream>>>(s1p, g1, be1, pr);
    k_s2<<<NBS_, 256, 0, stream>>>(a1, w2t, b2, g2, pr, s2p, pooled);
    k_fin2c<<<128, 256, 0, stream>>>(s2p, g2, be2, pr);
    k_s3<<<NPIX_*4/256, 256, 0, stream>>>(pr, pooled);
  } else {
    hipMemsetAsync(st, 0, 512*sizeof(float), stream);
    k_mom<<<256, 256, 0, stream>>>(xyz, points, nx, idx, st);
    k_fin0<<<1, 64, 0, stream>>>(w0, b0, g0, be0, st, pr);
    k_stage<1><<<1024, 256, 0, stream>>>(xyz, points, nx, idx, w0t, w1t, w2t, b0, b1, b2, pr, st, out);
    k_fin<<<1, 64, 0, stream>>>(g1, be1, st+32, st+96, pr+128, pr+192);
    k_stage<2><<<1024, 256, 0, stream>>>(xyz, points, nx, idx, w0t, w1t, w2t, b0, b1, b2, pr, st, out);
    k_fin<<<1, 128, 0, stream>>>(g2, be2, st+160, st+288, pr+256, pr+384);
    k_stage<3><<<1024, 256, 0, stream>>>(xyz, points, nx, idx, w0t, w1t, w2t, b0, b1, b2, pr, st, out);
  }
}